// Round 11
// baseline (2416.991 us; speedup 1.0000x reference)
//
#include <hip/hip_runtime.h>
#include <float.h>
#include <math.h>

#define NB 100000
#define SEQ 37
#define NTOK 1184  // 32*37
#define TKCH 16

typedef __attribute__((ext_vector_type(8))) short short8;
typedef __attribute__((ext_vector_type(4))) float floatx4;

__device__ __forceinline__ short f2bf(float f) {
  union { float f; unsigned u; } x; x.f = f;
  unsigned r = x.u + 0x7fff + ((x.u >> 16) & 1);  // RNE
  return (short)(r >> 16);
}

__device__ __forceinline__ float gelu_f(float v) {
  return 0.5f * v * (1.f + erff(v * 0.70710678118654752f));
}

// ============ MFMA GEMM, fp32 weights converted in-staging, fused epilogue =====
// C = [residual +] [gelu](A@W^T + bias + LT@B^T). Tile 64x128, BK=64, 4 waves
// (2x2, each 32x64), reg double-buffered. W staged fp32->bf16 into swizzled LDS
// (same layout as A). blockIdx.z: fused weight select (QKV) or K-split index.
// Kreal < K supported for zero-padded K (embed hp: 777 in K=832).
__global__ __launch_bounds__(256) void gemm_bt(const float* __restrict__ A, int lda,
                                               const float* __restrict__ W0,
                                               const float* __restrict__ W1,
                                               const float* __restrict__ W2,
                                               int ldw, int Kreal,
                                               const float* __restrict__ b0,
                                               const float* __restrict__ b1,
                                               const float* __restrict__ b2,
                                               const float* __restrict__ LT,
                                               const float* __restrict__ B0,
                                               const float* __restrict__ B1,
                                               const float* __restrict__ B2,
                                               float* __restrict__ C, size_t czstride,
                                               int ldc, int M, int K,
                                               int acc_flag, int gelu_flag,
                                               int ksn, float* __restrict__ part) {
  __shared__ short Al[2][64 * 64];
  __shared__ short Wl[2][128 * 64];
  const int z = blockIdx.z;
  const int kidx = (ksn > 1) ? z : 0;
  const float* Wz = (ksn > 1 || z == 0) ? W0 : (z == 1) ? W1 : W2;
  const float* bias = (ksn > 1 || z == 0) ? b0 : (z == 1) ? b1 : b2;
  const float* Bz = (ksn > 1 || z == 0) ? B0 : (z == 1) ? B1 : B2;
  if (ksn == 1) C += (size_t)z * czstride;
  const int nkc = (K >> 6) / ksn;
  const int kofs = kidx * nkc * 64;
  const int krel = Kreal - kofs;   // W-side bounds (crossing a row is OOB!)
  const int tid = threadIdx.x;
  const int wid = tid >> 6, lane = tid & 63;
  const int wr = wid >> 1, wc = wid & 1;
  const int bm = blockIdx.x * 64, bn = blockIdx.y * 128;
  const int arow = tid >> 2, s0 = (tid & 3) * 2;    // A: 4 thr/row, 2 slots
  const int wrow = tid >> 1, ws0 = (tid & 1) * 4;   // W: 2 thr/row, 4 slots

  floatx4 acc[2][4];
#pragma unroll
  for (int i = 0; i < 2; ++i)
#pragma unroll
    for (int j = 0; j < 4; ++j)
#pragma unroll
      for (int r = 0; r < 4; ++r) acc[i][j][r] = 0.f;

  const int ga = bm + arow;
  const bool aok = ga < M;
  const float* ap = A + (size_t)ga * lda + kofs;
  const float* wp = Wz + (size_t)(bn + wrow) * ldw + kofs;
  const int aswz = arow & 7, wswz = wrow & 7;

  float4 ar[4];
  float4 wreg[8];

#define LOAD_A(kc_)                                                        \
  {                                                                        \
    _Pragma("unroll") for (int j = 0; j < 2; ++j) {                        \
      const int slot = s0 + j;                                             \
      if (aok) {                                                           \
        ar[j * 2] = *(const float4*)(ap + (kc_)*64 + slot * 8);            \
        ar[j * 2 + 1] = *(const float4*)(ap + (kc_)*64 + slot * 8 + 4);    \
      } else {                                                             \
        ar[j * 2] = make_float4(0.f, 0.f, 0.f, 0.f);                      \
        ar[j * 2 + 1] = make_float4(0.f, 0.f, 0.f, 0.f);                  \
      }                                                                    \
    }                                                                      \
  }
#define LOAD_W(kc_)                                                        \
  {                                                                        \
    _Pragma("unroll") for (int j = 0; j < 4; ++j) {                        \
      const int slot = ws0 + j;                                            \
      const int kg = (kc_)*64 + slot * 8;                                  \
      if (kg + 7 < krel) {                                                 \
        wreg[j * 2] = *(const float4*)(wp + kg);                           \
        wreg[j * 2 + 1] = *(const float4*)(wp + kg + 4);                   \
      } else {                                                             \
        float t[8];                                                        \
        _Pragma("unroll") for (int e = 0; e < 8; ++e)                      \
            t[e] = (kg + e < krel) ? wp[kg + e] : 0.f;                     \
        wreg[j * 2] = make_float4(t[0], t[1], t[2], t[3]);                 \
        wreg[j * 2 + 1] = make_float4(t[4], t[5], t[6], t[7]);             \
      }                                                                    \
    }                                                                      \
  }
#define WRITE_A(buf_)                                                      \
  {                                                                        \
    _Pragma("unroll") for (int j = 0; j < 2; ++j) {                        \
      const int slot = s0 + j;                                             \
      short8 s;                                                            \
      s[0] = f2bf(ar[j * 2].x); s[1] = f2bf(ar[j * 2].y);                  \
      s[2] = f2bf(ar[j * 2].z); s[3] = f2bf(ar[j * 2].w);                  \
      s[4] = f2bf(ar[j * 2 + 1].x); s[5] = f2bf(ar[j * 2 + 1].y);          \
      s[6] = f2bf(ar[j * 2 + 1].z); s[7] = f2bf(ar[j * 2 + 1].w);          \
      *(short8*)&Al[buf_][arow * 64 + ((slot ^ aswz) << 3)] = s;           \
    }                                                                      \
  }
#define WRITE_W(buf_)                                                      \
  {                                                                        \
    _Pragma("unroll") for (int j = 0; j < 4; ++j) {                        \
      const int slot = ws0 + j;                                            \
      short8 s;                                                            \
      s[0] = f2bf(wreg[j * 2].x); s[1] = f2bf(wreg[j * 2].y);              \
      s[2] = f2bf(wreg[j * 2].z); s[3] = f2bf(wreg[j * 2].w);              \
      s[4] = f2bf(wreg[j * 2 + 1].x); s[5] = f2bf(wreg[j * 2 + 1].y);      \
      s[6] = f2bf(wreg[j * 2 + 1].z); s[7] = f2bf(wreg[j * 2 + 1].w);      \
      *(short8*)&Wl[buf_][wrow * 64 + ((slot ^ wswz) << 3)] = s;           \
    }                                                                      \
  }

  LOAD_W(0) LOAD_A(0)
  WRITE_A(0) WRITE_W(0)
  __syncthreads();

  for (int t = 0; t < nkc; ++t) {
    const int cur = t & 1, nxt = cur ^ 1;
    const bool more = (t + 1 < nkc);
    if (more) { LOAD_W(t + 1) LOAD_A(t + 1) }
#pragma unroll
    for (int ks = 0; ks < 2; ++ks) {
      short8 af[2], wf[4];
#pragma unroll
      for (int i = 0; i < 2; ++i) {
        const int row = wr * 32 + i * 16 + (lane & 15);
        const int sa = (ks * 4 + (lane >> 4)) ^ (row & 7);
        af[i] = *(const short8*)&Al[cur][row * 64 + sa * 8];
      }
#pragma unroll
      for (int j = 0; j < 4; ++j) {
        const int col = wc * 64 + j * 16 + (lane & 15);
        const int sw2 = (ks * 4 + (lane >> 4)) ^ (col & 7);
        wf[j] = *(const short8*)&Wl[cur][col * 64 + sw2 * 8];
      }
#pragma unroll
      for (int i = 0; i < 2; ++i)
#pragma unroll
        for (int j = 0; j < 4; ++j)
          acc[i][j] = __builtin_amdgcn_mfma_f32_16x16x32_bf16(af[i], wf[j], acc[i][j], 0, 0, 0);
    }
    if (more) { WRITE_A(nxt) WRITE_W(nxt) }
    __syncthreads();
  }
#undef LOAD_A
#undef LOAD_W
#undef WRITE_A
#undef WRITE_W

  if (ksn > 1) {
#pragma unroll
    for (int i = 0; i < 2; ++i) {
      const int gm0 = bm + wr * 32 + i * 16 + (lane >> 4) * 4;
#pragma unroll
      for (int r = 0; r < 4; ++r) {
        const int gm = gm0 + r;
        if (gm >= M) continue;
#pragma unroll
        for (int j = 0; j < 4; ++j) {
          const int gn = bn + wc * 64 + j * 16 + (lane & 15);
          part[((size_t)kidx * M + gm) * ldc + gn] = acc[i][j][r];
        }
      }
    }
    return;
  }

  float br[4][8];
  if (LT) {
#pragma unroll
    for (int j = 0; j < 4; ++j) {
      const int gn = bn + wc * 64 + j * 16 + (lane & 15);
      const float4 u0 = *(const float4*)(Bz + (size_t)gn * 8);
      const float4 u1 = *(const float4*)(Bz + (size_t)gn * 8 + 4);
      br[j][0] = u0.x; br[j][1] = u0.y; br[j][2] = u0.z; br[j][3] = u0.w;
      br[j][4] = u1.x; br[j][5] = u1.y; br[j][6] = u1.z; br[j][7] = u1.w;
    }
  }
#pragma unroll
  for (int i = 0; i < 2; ++i) {
    const int gm0 = bm + wr * 32 + i * 16 + (lane >> 4) * 4;
#pragma unroll
    for (int r = 0; r < 4; ++r) {
      const int gm = gm0 + r;
      if (gm >= M) continue;
      float lt[8];
      if (LT) {
        const float4 t0 = *(const float4*)(LT + ((size_t)z * NTOK + gm) * 8);
        const float4 t1 = *(const float4*)(LT + ((size_t)z * NTOK + gm) * 8 + 4);
        lt[0] = t0.x; lt[1] = t0.y; lt[2] = t0.z; lt[3] = t0.w;
        lt[4] = t1.x; lt[5] = t1.y; lt[6] = t1.z; lt[7] = t1.w;
      }
#pragma unroll
      for (int j = 0; j < 4; ++j) {
        const int gn = bn + wc * 64 + j * 16 + (lane & 15);
        float o = acc[i][j][r] + bias[gn];
        if (LT)
          o += lt[0] * br[j][0] + lt[1] * br[j][1] + lt[2] * br[j][2] + lt[3] * br[j][3] +
               lt[4] * br[j][4] + lt[5] * br[j][5] + lt[6] * br[j][6] + lt[7] * br[j][7];
        const size_t off = (size_t)gm * ldc + gn;
        if (acc_flag) o += C[off];
        if (gelu_flag) o = gelu_f(o);
        C[off] = o;
      }
    }
  }
}

// Generic K-split reduce: X += sum_{h<KS}(part_h) + bias + LT@B^T  (N=1024)
__global__ __launch_bounds__(256) void reduce_ks(const float* __restrict__ part,
                                                 const float* __restrict__ bias,
                                                 const float* __restrict__ LT,
                                                 const float* __restrict__ Bm,
                                                 float* __restrict__ X, int KS) {
  const int idx = blockIdx.x * 256 + threadIdx.x;
  if (idx >= NTOK * 1024) return;
  const int gm = idx >> 10, gn = idx & 1023;
  float s = 0.f;
  for (int h = 0; h < KS; ++h) s += part[(size_t)h * NTOK * 1024 + idx];
  const float* t = LT + (size_t)gm * 8;
  const float* bp = Bm + (size_t)gn * 8;
  s += t[0] * bp[0] + t[1] * bp[1] + t[2] * bp[2] + t[3] * bp[3] +
       t[4] * bp[4] + t[5] * bp[5] + t[6] * bp[6] + t[7] * bp[7];
  X[idx] += s + bias[gn];
}

// ============ small-M fp32 GEMM v2 (M=32) with K-split ==========================
__global__ __launch_bounds__(256) void gemm_sm2(const float* __restrict__ A, int lda,
                                                const float* __restrict__ W, int ldw,
                                                const float* __restrict__ bias,
                                                float* __restrict__ C, int ldc,
                                                float* __restrict__ part,
                                                int N, int K, int gelu_flag) {
  __shared__ float buf[8192];
  const int tid = threadIdx.x;
  const int col = tid >> 3, ksub = tid & 7;
  const int gcol = blockIdx.x * 32 + col;
  const int KS = gridDim.y, ky = blockIdx.y;
  const int kchunk = (((K + KS - 1) / KS) + 127) & ~127;
  const int kstart = ky * kchunk;
  const int kend = (kstart + kchunk < K) ? (kstart + kchunk) : K;
  const float* wp = W + (size_t)(gcol < N ? gcol : 0) * ldw;

  float acc[32];
#pragma unroll
  for (int m = 0; m < 32; ++m) acc[m] = 0.f;

  for (int kc = kstart; kc < kend; kc += 128) {
    __syncthreads();
#pragma unroll
    for (int q = 0; q < 4; ++q) {
      const int idx4 = q * 256 + tid;
      const int m = idx4 >> 5, j = (idx4 & 31) * 4;
      const int gk = kc + j;
      float4 v;
      if (gk + 3 < K) {
        v = *(const float4*)(A + (size_t)m * lda + gk);
      } else {
        v.x = (gk < K) ? A[(size_t)m * lda + gk] : 0.f;
        v.y = (gk + 1 < K) ? A[(size_t)m * lda + gk + 1] : 0.f;
        v.z = (gk + 2 < K) ? A[(size_t)m * lda + gk + 2] : 0.f;
        v.w = (gk + 3 < K) ? A[(size_t)m * lda + gk + 3] : 0.f;
      }
      *(float4*)&buf[m * 128 + j] = v;
    }
    __syncthreads();
#pragma unroll
    for (int kk = 0; kk < 4; ++kk) {
      const int j = kk * 32 + ksub * 4;
      const int gk = kc + j;
      float4 w4 = make_float4(0.f, 0.f, 0.f, 0.f);
      if (gcol < N && gk < K) {
        if (gk + 3 < K) {
          w4 = *(const float4*)(wp + gk);
        } else {
          w4.x = wp[gk];
          if (gk + 1 < K) w4.y = wp[gk + 1];
          if (gk + 2 < K) w4.z = wp[gk + 2];
        }
      }
#pragma unroll
      for (int m = 0; m < 32; ++m) {
        const float4 a4 = *(const float4*)&buf[m * 128 + j];
        acc[m] += a4.x * w4.x + a4.y * w4.y + a4.z * w4.z + a4.w * w4.w;
      }
    }
  }
  __syncthreads();
#pragma unroll
  for (int m = 0; m < 32; ++m) buf[m * 256 + ksub * 32 + col] = acc[m];
  __syncthreads();
#pragma unroll
  for (int g = 0; g < 4; ++g) {
    const int idx = g * 256 + tid;
    const int m = idx >> 5, c = idx & 31;
    float s = 0.f;
#pragma unroll
    for (int h = 0; h < 8; ++h) s += buf[m * 256 + h * 32 + c];
    const int gc = blockIdx.x * 32 + c;
    if (gc < N) {
      if (KS == 1) {
        float o = s + bias[gc];
        if (gelu_flag) o = gelu_f(o);
        C[(size_t)m * ldc + gc] = o;
      } else {
        part[((size_t)ky * 32 + m) * N + gc] = s;
      }
    }
  }
}

__global__ __launch_bounds__(256) void reduce_sm(const float* __restrict__ part,
                                                 const float* __restrict__ bias,
                                                 float* __restrict__ C, int ldc,
                                                 int N, int KS, int gelu_flag) {
  const int idx = blockIdx.x * 256 + threadIdx.x;
  if (idx >= 32 * N) return;
  const int m = idx / N, c = idx - m * N;
  float s = 0.f;
  for (int h = 0; h < KS; ++h) s += part[((size_t)h * 32 + m) * N + c];
  float o = s + bias[c];
  if (gelu_flag) o = gelu_f(o);
  C[(size_t)m * ldc + c] = o;
}

// ============ sims ==============================================================
__global__ __launch_bounds__(256) void sims_kernel(const float* __restrict__ cur,
                                                   const float* __restrict__ bank,
                                                   float* __restrict__ sims) {
  __shared__ float Bs[32][132];
  __shared__ float Cs[32][36];
  const int tid = threadIdx.x;
  const int tx = tid & 7;
  const int ty = tid >> 3;
  const int n0 = blockIdx.x * 128;
  const int srow = tid >> 1;
  const int spart = tid & 1;
  const int cb = tid >> 3;
  const int ck = (tid & 7) * 4;

  float acc[4][4] = {{0.f,0.f,0.f,0.f},{0.f,0.f,0.f,0.f},
                     {0.f,0.f,0.f,0.f},{0.f,0.f,0.f,0.f}};

  const bool rok = (n0 + srow) < NB;
  const float* bp = bank + (size_t)(n0 + srow) * 768 + spart * 16;
  const float* cp = cur + (size_t)cb * 768 + ck;

  for (int kc = 0; kc < 768; kc += 32) {
    __syncthreads();
#pragma unroll
    for (int jj = 0; jj < 4; ++jj) {
      float4 v = rok ? *(const float4*)(bp + kc + jj * 4)
                     : make_float4(0.f, 0.f, 0.f, 0.f);
      const int kk = spart * 16 + jj * 4;
      Bs[kk + 0][srow] = v.x; Bs[kk + 1][srow] = v.y;
      Bs[kk + 2][srow] = v.z; Bs[kk + 3][srow] = v.w;
    }
    {
      float4 v = *(const float4*)(cp + kc);
      Cs[ck + 0][cb] = v.x; Cs[ck + 1][cb] = v.y;
      Cs[ck + 2][cb] = v.z; Cs[ck + 3][cb] = v.w;
    }
    __syncthreads();
#pragma unroll
    for (int kk = 0; kk < 32; ++kk) {
      float4 av = *(const float4*)&Bs[kk][ty * 4];
      float4 bv = *(const float4*)&Cs[kk][tx * 4];
      float a4[4] = {av.x, av.y, av.z, av.w};
      float b4[4] = {bv.x, bv.y, bv.z, bv.w};
#pragma unroll
      for (int i = 0; i < 4; ++i)
#pragma unroll
        for (int j = 0; j < 4; ++j) acc[i][j] += a4[i] * b4[j];
    }
  }
  const int n = n0 + ty * 4;
#pragma unroll
  for (int j = 0; j < 4; ++j) {
    const int b = tx * 4 + j;
    float4 o = make_float4(acc[0][j], acc[1][j], acc[2][j], acc[3][j]);
    if (n + 3 < NB) {
      *(float4*)(sims + (size_t)b * NB + n) = o;
    } else {
      float oo[4] = {o.x, o.y, o.z, o.w};
      for (int i = 0; i < 4; ++i)
        if (n + i < NB) sims[(size_t)b * NB + n + i] = oo[i];
    }
  }
}

// ===================== top-K ====================================================
__global__ __launch_bounds__(256) void topk_stage1(const float* __restrict__ sims,
                                                   float* __restrict__ cv,
                                                   int* __restrict__ ci) {
  __shared__ float ss[4096];
  __shared__ int si[4096];
  __shared__ float wv[4];
  __shared__ int wi[4];
  const int chunk = blockIdx.x, b = blockIdx.y, tid = threadIdx.x;
  const int start = chunk * (NB / TKCH), end = start + (NB / TKCH);
  float ls[16]; int li[16];
#pragma unroll
  for (int i = 0; i < 16; ++i) { ls[i] = -FLT_MAX; li[i] = 0x7fffffff; }
  const float* row = sims + (size_t)b * NB;
  float lmin = -FLT_MAX;
  for (int n = start + tid; n < end; n += 256) {
    float v = row[n];
    if (v > lmin) {
      int p = 15;
      while (p > 0 && ls[p - 1] < v) { ls[p] = ls[p - 1]; li[p] = li[p - 1]; --p; }
      ls[p] = v; li[p] = n;
      lmin = ls[15];
    }
  }
#pragma unroll
  for (int i = 0; i < 16; ++i) { ss[i * 256 + tid] = ls[i]; si[i * 256 + tid] = li[i]; }
  __syncthreads();
  for (int round = 0; round < 16; ++round) {
    float bv = -FLT_MAX; int bi = 0x7fffffff;
#pragma unroll
    for (int i = 0; i < 16; ++i) {
      float v = ss[i * 256 + tid]; int ix = si[i * 256 + tid];
      if (v > bv || (v == bv && ix < bi)) { bv = v; bi = ix; }
    }
#pragma unroll
    for (int s = 32; s; s >>= 1) {
      float ov = __shfl_down(bv, s); int oi = __shfl_down(bi, s);
      if (ov > bv || (ov == bv && oi < bi)) { bv = ov; bi = oi; }
    }
    if ((tid & 63) == 0) { wv[tid >> 6] = bv; wi[tid >> 6] = bi; }
    __syncthreads();
    if (tid == 0) {
      bv = wv[0]; bi = wi[0];
      for (int w = 1; w < 4; ++w)
        if (wv[w] > bv || (wv[w] == bv && wi[w] < bi)) { bv = wv[w]; bi = wi[w]; }
      cv[(b * TKCH + chunk) * 16 + round] = bv;
      ci[(b * TKCH + chunk) * 16 + round] = bi;
      wi[0] = bi;
    }
    __syncthreads();
    bi = wi[0];
#pragma unroll
    for (int i = 0; i < 16; ++i)
      if (si[i * 256 + tid] == bi) ss[i * 256 + tid] = -FLT_MAX;
    __syncthreads();
  }
}

__global__ __launch_bounds__(256) void topk_stage2(const float* __restrict__ cv,
                                                   const int* __restrict__ ci,
                                                   float* __restrict__ tks,
                                                   int* __restrict__ tki) {
  __shared__ float wv[4];
  __shared__ int wi[4];
  __shared__ int bw;
  const int b = blockIdx.x, tid = threadIdx.x;
  float val = cv[b * 256 + tid];
  int idx = ci[b * 256 + tid];
  for (int round = 0; round < 16; ++round) {
    float bv = val; int bi = idx;
#pragma unroll
    for (int s = 1; s < 64; s <<= 1) {
      float ov = __shfl_xor(bv, s); int oi = __shfl_xor(bi, s);
      if (ov > bv || (ov == bv && oi < bi)) { bv = ov; bi = oi; }
    }
    if ((tid & 63) == 0) { wv[tid >> 6] = bv; wi[tid >> 6] = bi; }
    __syncthreads();
    if (tid == 0) {
      bv = wv[0]; bi = wi[0];
      for (int w = 1; w < 4; ++w)
        if (wv[w] > bv || (wv[w] == bv && wi[w] < bi)) { bv = wv[w]; bi = wi[w]; }
      tks[b * 16 + round] = bv; tki[b * 16 + round] = bi;
      bw = bi;
    }
    __syncthreads();
    if (idx == bw) val = -FLT_MAX;
  }
}

// ===================== small copy/assembly kernels ==============================
__global__ void sem_kernel(const float* __restrict__ bank, const float* __restrict__ tks,
                           const int* __restrict__ tki, float* __restrict__ sem) {
  int slot = blockIdx.x;
  float s = tks[slot]; int idx = tki[slot];
  for (int i = threadIdx.x; i < 768; i += 256)
    sem[(size_t)slot * 768 + i] = bank[(size_t)idx * 768 + i] * s;
}

// HIN stride 832, zero-padded k>=777
__global__ void build_hist_in(const float* __restrict__ img, const float* __restrict__ pr,
                              float* __restrict__ out) {
  int r = blockIdx.x;
  for (int i = threadIdx.x; i < 832; i += 256)
    out[(size_t)r * 832 + i] = (i < 768) ? img[(size_t)r * 768 + i]
                             : (i < 777) ? pr[r * 9 + (i - 768)] : 0.f;
}

__global__ void build_img_in(const float* __restrict__ goal, const float* __restrict__ sub,
                             const float* __restrict__ bea, const float* __restrict__ sem,
                             float* __restrict__ out) {
  int r = blockIdx.x;
  const float* src = (r < 32) ? goal + (size_t)r * 768
                   : (r < 64) ? sub + (size_t)(r - 32) * 768
                   : (r < 96) ? bea + (size_t)(r - 64) * 768
                              : sem + (size_t)(r - 96) * 768;
  for (int i = threadIdx.x; i < 768; i += 256) out[(size_t)r * 768 + i] = src[i];
}

__global__ void assemble_x(const float* __restrict__ th, const float* __restrict__ ti,
                           const float* __restrict__ tp, const float* __restrict__ plan,
                           float* __restrict__ x) {
  int r = blockIdx.x;
  int b = r / SEQ, tok = r - b * SEQ;
  const float* src;
  if (tok == 0) src = plan;
  else if (tok <= 16) src = th + (size_t)(b * 16 + tok - 1) * 1024;
  else if (tok <= 19) src = ti + (size_t)((tok - 17) * 32 + b) * 1024;
  else if (tok <= 35) src = ti + (size_t)(96 + b * 16 + (tok - 20)) * 1024;
  else src = tp + (size_t)b * 1024;
  for (int i = threadIdx.x; i < 1024; i += 256) x[(size_t)r * 1024 + i] = src[i];
}

__global__ void build_ref(const float* __restrict__ ps, const float* __restrict__ anc,
                          float* __restrict__ ref) {
  int b = blockIdx.x;
  for (int i = threadIdx.x; i < 1027; i += 256)
    ref[(size_t)b * 1027 + i] = (i < 1024) ? ps[(size_t)b * 1024 + i] : anc[b * 3 + (i - 1024)];
}

// ===================== layernorm (+fused LoRA-down, nz matrices) ===============
__device__ __forceinline__ float block_sum256(float v, float* red) {
#pragma unroll
  for (int s = 32; s; s >>= 1) v += __shfl_down(v, s);
  if ((threadIdx.x & 63) == 0) red[threadIdx.x >> 6] = v;
  __syncthreads();
  float tot = red[0] + red[1] + red[2] + red[3];
  __syncthreads();
  return tot;
}

__global__ __launch_bounds__(256) void ln_kernel(const float* __restrict__ in, int in_stride,
                                                 float* __restrict__ out,
                                                 const float* __restrict__ g,
                                                 const float* __restrict__ bt,
                                                 const float* __restrict__ A0,
                                                 const float* __restrict__ A1,
                                                 const float* __restrict__ A2,
                                                 int nz, float* __restrict__ lt) {
  __shared__ float red[4];
  __shared__ float red2[4][8];
  const float* xr = in + (size_t)blockIdx.x * in_stride;
  const int tid = threadIdx.x;
  const int wave = tid >> 6, lane = tid & 63;
  float v[4];
#pragma unroll
  for (int i = 0; i < 4; ++i) v[i] = xr[tid + 256 * i];
  float mean = block_sum256(v[0] + v[1] + v[2] + v[3], red) * (1.f / 1024.f);
  float sq = 0.f;
#pragma unroll
  for (int i = 0; i < 4; ++i) { float d = v[i] - mean; sq += d * d; }
  float var = block_sum256(sq, red) * (1.f / 1024.f);
  float inv = rsqrtf(var + 1e-5f);
  float* orow = out + (size_t)blockIdx.x * 1024;
  float nv[4];
#pragma unroll
  for (int i = 0; i < 4; ++i) {
    int c = tid + 256 * i;
    nv[i] = (v[i] - mean) * inv * g[c] + bt[c];
    orow[c] = nv[i];
  }
  for (int z = 0; z < nz; ++z) {
    const float* Am = (z == 0) ? A0 : (z == 1) ? A1 : A2;
    float p[8];
#pragma unroll
    for (int r = 0; r < 8; ++r) {
      float s = 0.f;
#pragma unroll
      for (int i = 0; i < 4; ++i) s += nv[i] * Am[r * 1024 + tid + 256 * i];
      p[r] = s;
    }
#pragma unroll
    for (int sh = 1; sh < 64; sh <<= 1) {
#pragma unroll
      for (int r = 0; r < 8; ++r) p[r] += __shfl_xor(p[r], sh);
    }
    if (lane == 0) {
#pragma unroll
      for (int r = 0; r < 8; ++r) red2[wave][r] = p[r];
    }
    __syncthreads();
    if (tid < 8)
      lt[((size_t)z * NTOK + blockIdx.x) * 8 + tid] =
          red2[0][tid] + red2[1][tid] + red2[2][tid] + red2[3][tid];
    __syncthreads();
  }
}

// ===================== LoRA down (standalone, for o/f2 inputs) ==================
__global__ __launch_bounds__(256) void lora_down(const float* __restrict__ h,
                                                 const float* __restrict__ A0,
                                                 const float* __restrict__ A1,
                                                 const float* __restrict__ A2,
                                                 float* __restrict__ lt, int K) {
  __shared__ float red[4][8];
  const int m = blockIdx.x, z = blockIdx.y;
  const int tid = threadIdx.x, wave = tid >> 6, lane = tid & 63;
  const float* A = (z == 0) ? A0 : (z == 1) ? A1 : A2;
  float p[8] = {0.f, 0.f, 0.f, 0.f, 0.f, 0.f, 0.f, 0.f};
  for (int kk = tid; kk < K; kk += 256) {
    float hv = h[(size_t)m * K + kk];
#pragma unroll
    for (int r = 0; r < 8; ++r) p[r] += hv * A[r * K + kk];
  }
#pragma unroll
  for (int s = 1; s < 64; s <<= 1) {
#pragma unroll
    for (int r = 0; r < 8; ++r) p[r] += __shfl_xor(p[r], s);
  }
  if (lane == 0) {
#pragma unroll
    for (int r = 0; r < 8; ++r) red[wave][r] = p[r];
  }
  __syncthreads();
  if (tid < 8)
    lt[((size_t)z * NTOK + m) * 8 + tid] =
        red[0][tid] + red[1][tid] + red[2][tid] + red[3][tid];
}

// ===================== attention ================================================
__global__ __launch_bounds__(256) void attn_kernel(const float* __restrict__ q,
                                                   const float* __restrict__ k,
                                                   const float* __restrict__ v,
                                                   float* __restrict__ ao) {
  __shared__ float qs[SEQ * 64], ks[SEQ * 64], vs[SEQ * 64], sc[SEQ * 40];
  const int head = blockIdx.x, b = blockIdx.y, tid = threadIdx.x;
  const size_t base = ((size_t)b * SEQ) * 1024 + head * 64;
  for (int i = tid; i < SEQ * 64; i += 256) {
    int s = i >> 6, d = i & 63;
    size_t off = base + (size_t)s * 1024 + d;
    qs[i] = q[off]; ks[i] = k[off]; vs[i] = v[off];
  }
  __syncthreads();
  for (int p = tid; p < SEQ * SEQ; p += 256) {
    int s = p / SEQ, t = p - s * SEQ;
    float acc = 0.f;
#pragma unroll 16
    for (int d = 0; d < 64; ++d) acc += qs[s * 64 + d] * ks[t * 64 + d];
    sc[s * 40 + t] = acc * 0.125f;
  }
  __syncthreads();
  if (tid < SEQ) {
    float m = -FLT_MAX;
    for (int t = 0; t < SEQ; ++t) m = fmaxf(m, sc[tid * 40 + t]);
    float sum = 0.f;
    for (int t = 0; t < SEQ; ++t) { float e = expf(sc[tid * 40 + t] - m); sc[tid * 40 + t] = e; sum += e; }
    float inv = 1.f / sum;
    for (int t = 0; t < SEQ; ++t) sc[tid * 40 + t] *= inv;
  }
  __syncthreads();
  for (int i = tid; i < SEQ * 64; i += 256) {
    int s = i >> 6, d = i & 63;
    float acc = 0.f;
    for (int t = 0; t < SEQ; ++t) acc += sc[s * 40 + t] * vs[t * 64 + d];
    ao[base + (size_t)s * 1024 + d] = acc;
  }
}

// ===================== host =====================================================
extern "C" void kernel_launch(void* const* d_in, const int* in_sizes, int n_in,
                              void* d_out, int out_size, void* d_ws, size_t ws_size,
                              hipStream_t stream) {
  const float* hist_img = (const float*)d_in[0];
  const float* cur      = (const float*)d_in[1];
  const float* goal     = (const float*)d_in[2];
  const float* sub      = (const float*)d_in[3];
  const float* bea      = (const float*)d_in[4];
  const float* hist_pr  = (const float*)d_in[5];
  const float* prop     = (const float*)d_in[6];
  const float* bank     = (const float*)d_in[7];
  const float* hpW = (const float*)d_in[8];  const float* hpb = (const float*)d_in[9];
  const float* ipW = (const float*)d_in[10]; const float* ipb = (const float*)d_in[11];
  const float* ppW = (const float*)d_in[12]; const float* ppb = (const float*)d_in[13];
  const float* plan = (const float*)d_in[14];
  const float* ln1g = (const float*)d_in[15]; const float* ln1b = (const float*)d_in[16];
  const float* ln2g = (const float*)d_in[17]; const float* ln2b = (const float*)d_in[18];
  const float* qW = (const float*)d_in[19]; const float* qA = (const float*)d_in[20];
  const float* qB = (const float*)d_in[21]; const float* qb = (const float*)d_in[22];
  const float* kW = (const float*)d_in[23]; const float* kA = (const float*)d_in[24];
  const float* kB = (const float*)d_in[25]; const float* kb = (const float*)d_in[26];
  const float* vW = (const float*)d_in[27]; const float* vA = (const float*)d_in[28];
  const float* vB = (const float*)d_in[29]; const float* vb = (const float*)d_in[30];
  const float* oW = (const float*)d_in[31]; const float* oA = (const float*)d_in[32];
  const float* oB = (const float*)d_in[33]; const float* ob = (const float*)d_in[34];
  const float* f1W = (const float*)d_in[35]; const float* f1A = (const float*)d_in[36];
  const float* f1B = (const float*)d_in[37]; const float* f1b = (const float*)d_in[38];
  const float* f2W = (const float*)d_in[39]; const float* f2A = (const float*)d_in[40];
  const float* f2B = (const float*)d_in[41]; const float* f2b = (const float*)d_in[42];
  const float* flng = (const float*)d_in[43]; const float* flnb = (const float*)d_in[44];
  const float* ahW1 = (const float*)d_in[45]; const float* ahb1 = (const float*)d_in[46];
  const float* ahW2 = (const float*)d_in[47]; const float* ahb2 = (const float*)d_in[48];
  const float* rhW1 = (const float*)d_in[49]; const float* rhb1 = (const float*)d_in[50];
  const float* rhW2 = (const float*)d_in[51]; const float* rhb2 = (const float*)d_in[52];
  const float* shW = (const float*)d_in[53]; const float* shb = (const float*)d_in[54];
  float* out = (float*)d_out;

  float* ws  = (float*)d_ws;
  float* F1O = ws;
  float* SIMS = ws;
  float* X   = F1O + (size_t)NTOK * 4096;
  float* Hb  = X  + (size_t)NTOK * 1024;
  float* Qb  = Hb + (size_t)NTOK * 1024;
  float* Kb  = Qb + (size_t)NTOK * 1024;
  float* Vb  = Kb + (size_t)NTOK * 1024;
  float* AOb = Vb + (size_t)NTOK * 1024;
  float* LT  = AOb + (size_t)NTOK * 1024;      // 3*NTOK*8
  float* SEM = LT + (size_t)3 * NTOK * 8;
  float* HIN = SEM + (size_t)512 * 768;        // 512*832 (padded)
  float* TKS = HIN + (size_t)512 * 832;
  int*   TKI = (int*)(TKS + 512);
  float* PS  = TKS + 1024;
  float* HH  = PS + 32 * 1024;
  float* REF = HH + 32 * 1024;
  float* CV  = REF + 32 * 1027;
  int*   CI  = (int*)(CV + 32 * 256);
  float* PART = (float*)(CI + 32 * 256);       // heads: 8*32*1024
  float* PF2 = PART + 8 * 32 * 1024;           // K-split partials: 4*NTOK*1024

  const size_t czs = (size_t)NTOK * 1024;

  auto gemms = [&](const float* A, int lda, const float* W, int ldw, const float* bias,
                   float* C, int ldc, int N, int K, int geluf, int KS) {
    gemm_sm2<<<dim3((N + 31) / 32, KS), 256, 0, stream>>>(A, lda, W, ldw, bias,
                                                          C, ldc, PART, N, K, geluf);
    if (KS > 1)
      reduce_sm<<<(32 * N + 255) / 256, 256, 0, stream>>>(PART, bias, C, ldc, N, KS, geluf);
  };

  // ---- retrieval ----
  sims_kernel<<<(NB + 127) / 128, 256, 0, stream>>>(cur, bank, SIMS);
  topk_stage1<<<dim3(TKCH, 32), 256, 0, stream>>>(SIMS, CV, CI);
  topk_stage2<<<32, 256, 0, stream>>>(CV, CI, TKS, TKI);
  sem_kernel<<<512, 256, 0, stream>>>(bank, TKS, TKI, SEM);

  // ---- token embedding (direct fp32-W MFMA GEMMs) ----
  build_hist_in<<<512, 256, 0, stream>>>(hist_img, hist_pr, HIN);
  build_img_in<<<608, 256, 0, stream>>>(goal, sub, bea, SEM, AOb);
  gemm_bt<<<dim3(8, 8, 1), 256, 0, stream>>>(
      HIN, 832, hpW, hpW, hpW, 777, 777, hpb, hpb, hpb,
      nullptr, nullptr, nullptr, nullptr, Qb, 0, 1024, 512, 832, 0, 0, 1, nullptr);
  gemm_bt<<<dim3(10, 8, 1), 256, 0, stream>>>(
      AOb, 768, ipW, ipW, ipW, 768, 768, ipb, ipb, ipb,
      nullptr, nullptr, nullptr, nullptr, Kb, 0, 1024, 608, 768, 0, 0, 1, nullptr);
  gemms(prop, 9, ppW, 9, ppb, Vb, 1024, 1024, 9, 0, 1);
  assemble_x<<<NTOK, 256, 0, stream>>>(Qb, Kb, Vb, plan, X);

  // ---- transformer layers ----
  const int mblk = (NTOK + 63) / 64;  // 19
  for (int l = 0; l < 6; ++l) {
    const size_t wO = (size_t)l * 1024 * 1024, aO = (size_t)l * 8 * 1024,
                 bO = (size_t)l * 1024 * 8, biO = (size_t)l * 1024;
    const size_t w4O = (size_t)l * 4096 * 1024, a4O = (size_t)l * 8 * 4096,
                 b4O = (size_t)l * 4096 * 8, bi4O = (size_t)l * 4096;
    // ln1 + fused qkv lora-down
    ln_kernel<<<NTOK, 256, 0, stream>>>(X, 1024, Hb, ln1g + biO, ln1b + biO,
                                        qA + aO, kA + aO, vA + aO, 3, LT);
    gemm_bt<<<dim3(mblk, 8, 3), 256, 0, stream>>>(
        Hb, 1024, qW + wO, kW + wO, vW + wO, 1024, 1024, qb + biO, kb + biO, vb + biO,
        LT, qB + bO, kB + bO, vB + bO, Qb, czs, 1024, NTOK, 1024, 0, 0, 1, nullptr);
    attn_kernel<<<dim3(16, 32), 256, 0, stream>>>(Qb, Kb, Vb, AOb);
    lora_down<<<dim3(NTOK, 1), 256, 0, stream>>>(AOb, oA + aO, oA + aO, oA + aO, LT, 1024);
    gemm_bt<<<dim3(mblk, 8, 2), 256, 0, stream>>>(        // o: K-split x2
        AOb, 1024, oW + wO, oW + wO, oW + wO, 1024, 1024, ob + biO, ob + biO, ob + biO,
        nullptr, nullptr, nullptr, nullptr, nullptr, 0, 1024, NTOK, 1024, 0, 0, 2, PF2);
    reduce_ks<<<(NTOK * 1024 + 255) / 256, 256, 0, stream>>>(PF2, ob + biO, LT,
                                                             oB + bO, X, 2);
    // ln2 + fused f1 lora-down
    ln_kernel<<<NTOK, 256, 0, stream>>>(X, 1024, Hb, ln2g + biO, ln2b + biO,
                                        f1A + aO, f1A + aO, f1A + aO, 1, LT);
    gemm_bt<<<dim3(mblk, 32, 1), 256, 0, stream>>>(
        Hb, 1024, f1W + w4O, f1W + w4O, f1W + w4O, 1024, 1024,
        f1b + bi4O, f1b + bi4O, f1b + bi4O,
        LT, f1B + b4O, f1B + b4O, f1B + b4O, F1O, 0, 4096, NTOK, 1024, 0, 1, 1, nullptr);
    lora_down<<<dim3(NTOK, 1), 256, 0, stream>>>(F1O, f2A + a4O, f2A + a4O, f2A + a4O, LT, 4096);
    gemm_bt<<<dim3(mblk, 8, 4), 256, 0, stream>>>(        // f2: K-split x4
        F1O, 4096, f2W + w4O, f2W + w4O, f2W + w4O, 4096, 4096,
        f2b + biO, f2b + biO, f2b + biO,
        nullptr, nullptr, nullptr, nullptr, nullptr, 0, 1024, NTOK, 4096, 0, 0, 4, PF2);
    reduce_ks<<<(NTOK * 1024 + 255) / 256, 256, 0, stream>>>(PF2, f2b + biO, LT,
                                                             f2B + bO, X, 4);
  }

  // ---- heads ----
  ln_kernel<<<32, 256, 0, stream>>>(X, SEQ * 1024, PS, flng, flnb,
                                    nullptr, nullptr, nullptr, 0, nullptr);
  gemms(PS, 1024, ahW1, 1024, ahb1, HH, 1024, 1024, 1024, 1, 8);
  gemms(HH, 1024, ahW2, 1024, ahb2, out, 3, 3, 1024, 0, 8);
  build_ref<<<32, 256, 0, stream>>>(PS, out, REF);
  gemms(REF, 1027, rhW1, 1027, rhb1, HH, 1024, 1024, 1027, 1, 8);
  gemms(HH, 1024, rhW2, 1024, rhb2, out + 96, 24, 24, 1024, 0, 8);
  gemms(PS, 1024, shW, 1024, shb, out + 864, 1, 1, 1024, 0, 8);
}

// Round 12
// 1692.588 us; speedup vs baseline: 1.4280x; 1.4280x over previous
//
#include <hip/hip_runtime.h>
#include <float.h>
#include <math.h>

#define NB 100000
#define SEQ 37
#define NTOK 1184  // 32*37
#define TKCH 16

typedef __attribute__((ext_vector_type(8))) short short8;
typedef __attribute__((ext_vector_type(4))) float floatx4;

__device__ __forceinline__ short f2bf(float f) {
  union { float f; unsigned u; } x; x.f = f;
  unsigned r = x.u + 0x7fff + ((x.u >> 16) & 1);  // RNE
  return (short)(r >> 16);
}

__device__ __forceinline__ float gelu_f(float v) {
  return 0.5f * v * (1.f + erff(v * 0.70710678118654752f));
}

// ===================== all-layer weight conversion ==============================
// Tiled+swizzled bf16: tile(np,kc) = 128 rows x 64 k; element (row,col) at
// row*64 + ((col>>3)^(row&7))*8 + (col&7). Dst-linear iteration (dense stores).
__global__ __launch_bounds__(256) void wconv_all(const float* __restrict__ qW,
                                                 const float* __restrict__ kW,
                                                 const float* __restrict__ vW,
                                                 const float* __restrict__ oW,
                                                 const float* __restrict__ f1W,
                                                 const float* __restrict__ f2W,
                                                 short* __restrict__ wb) {
  const int l = blockIdx.x / 1536;
  const int t = blockIdx.x - l * 1536;
  const float* src; int Kd; size_t doff; int np, kc;
  if (t < 512) {
    const int w = t >> 7, ti = t & 127;
    const float* base = (w == 0) ? qW : (w == 1) ? kW : (w == 2) ? vW : oW;
    src = base + (size_t)l * 1024 * 1024;
    Kd = 1024; np = ti >> 4; kc = ti & 15;
    doff = (size_t)w * 1048576 + ((size_t)np * 16 + kc) * 8192;
  } else if (t < 1024) {
    const int ti = t - 512;
    src = f1W + (size_t)l * 4096 * 1024;
    Kd = 1024; np = ti >> 4; kc = ti & 15;
    doff = (size_t)4 * 1048576 + ((size_t)np * 16 + kc) * 8192;
  } else {
    const int ti = t - 1024;
    src = f2W + (size_t)l * 1024 * 4096;
    Kd = 4096; np = ti >> 6; kc = ti & 63;
    doff = (size_t)8 * 1048576 + ((size_t)np * 64 + kc) * 8192;
  }
  short* dst = wb + (size_t)l * 12 * 1048576 + doff;
  const float* sp = src + (size_t)(np * 128) * Kd + kc * 64;
  const int tid = threadIdx.x;
#pragma unroll
  for (int q = 0; q < 4; ++q) {
    const int d = q * 256 + tid;
    const int row = d >> 3, slot = d & 7;
    const int ss = slot ^ (row & 7);
    const float* s = sp + (size_t)row * Kd + ss * 8;
    const float4 u0 = *(const float4*)s;
    const float4 u1 = *(const float4*)(s + 4);
    short8 v;
    v[0] = f2bf(u0.x); v[1] = f2bf(u0.y); v[2] = f2bf(u0.z); v[3] = f2bf(u0.w);
    v[4] = f2bf(u1.x); v[5] = f2bf(u1.y); v[6] = f2bf(u1.z); v[7] = f2bf(u1.w);
    *(short8*)(dst + (size_t)d * 8) = v;
  }
}

// ===================== embed weight conversion (hpW K=777->832, ipW K=768) =====
__global__ __launch_bounds__(256) void wconv_embed(const float* __restrict__ hpW,
                                                   const float* __restrict__ ipW,
                                                   short* __restrict__ wbe) {
  const int t = blockIdx.x;  // 0..199: 104 hp tiles (np*13+kc), 96 ip (np*12+kc)
  const float* src; int Kd, np, kc; size_t doff;
  if (t < 104) { src = hpW; Kd = 777; np = t / 13; kc = t - np * 13; doff = (size_t)t * 8192; }
  else { const int ti = t - 104; src = ipW; Kd = 768; np = ti / 12; kc = ti - np * 12;
         doff = (size_t)t * 8192; }
  short* dst = wbe + doff;
  const int tid = threadIdx.x;
#pragma unroll
  for (int q = 0; q < 4; ++q) {
    const int d = q * 256 + tid;
    const int row = d >> 3, slot = d & 7;
    const int ss = slot ^ (row & 7);
    const int gk0 = kc * 64 + ss * 8;
    const float* s = src + (size_t)(np * 128 + row) * Kd;
    short8 v;
#pragma unroll
    for (int e = 0; e < 8; ++e) v[e] = (gk0 + e < Kd) ? f2bf(s[gk0 + e]) : (short)0;
    *(short8*)(dst + (size_t)d * 8) = v;
  }
}

// ============ MFMA GEMM, bf16-tiled weights, fused LoRA/residual/gelu ==========
// Tile 64x128, BK=64, 4 waves (2x2, each 32x64). ksn>1: z = K-split -> partials.
__global__ __launch_bounds__(256) void gemm_bt(const float* __restrict__ A, int lda,
                                               const short* __restrict__ WT, size_t wzstride,
                                               const float* __restrict__ b0,
                                               const float* __restrict__ b1,
                                               const float* __restrict__ b2,
                                               const float* __restrict__ LT,
                                               const float* __restrict__ B0,
                                               const float* __restrict__ B1,
                                               const float* __restrict__ B2,
                                               float* __restrict__ C, size_t czstride,
                                               int ldc, int M, int K,
                                               int acc_flag, int gelu_flag,
                                               int ksn, float* __restrict__ part) {
  __shared__ short Al[2][64 * 64];
  __shared__ short Wl[2][128 * 64];
  const int z = blockIdx.z;
  const int kidx = (ksn > 1) ? z : 0;
  const float* bias = (ksn > 1 || z == 0) ? b0 : (z == 1) ? b1 : b2;
  const float* Bz = (ksn > 1 || z == 0) ? B0 : (z == 1) ? B1 : B2;
  if (ksn == 1) C += (size_t)z * czstride;
  const int nkc_tot = K >> 6;
  const int nkc = nkc_tot / ksn;
  const short* wt = WT + (size_t)((ksn > 1) ? 0 : z) * wzstride +
                    ((size_t)blockIdx.y * nkc_tot + (size_t)kidx * nkc) * 8192;
  const int tid = threadIdx.x;
  const int wid = tid >> 6, lane = tid & 63;
  const int wr = wid >> 1, wc = wid & 1;
  const int bm = blockIdx.x * 64, bn = blockIdx.y * 128;
  const int arow = tid >> 2;
  const int s0 = (tid & 3) * 2;

  floatx4 acc[2][4];
#pragma unroll
  for (int i = 0; i < 2; ++i)
#pragma unroll
    for (int j = 0; j < 4; ++j)
#pragma unroll
      for (int r = 0; r < 4; ++r) acc[i][j][r] = 0.f;

  const int ga = bm + arow;
  const bool aok = ga < M;
  const float* ap = A + (size_t)ga * lda + (size_t)kidx * nkc * 64;
  const int aswz = arow & 7;

  float4 ar[4];
  short8 wreg[4];

#define LOAD_A(kc_)                                                        \
  {                                                                        \
    _Pragma("unroll") for (int j = 0; j < 2; ++j) {                        \
      const int slot = s0 + j;                                             \
      if (aok) {                                                           \
        ar[j * 2] = *(const float4*)(ap + (kc_)*64 + slot * 8);            \
        ar[j * 2 + 1] = *(const float4*)(ap + (kc_)*64 + slot * 8 + 4);    \
      } else {                                                             \
        ar[j * 2] = make_float4(0.f, 0.f, 0.f, 0.f);                      \
        ar[j * 2 + 1] = make_float4(0.f, 0.f, 0.f, 0.f);                  \
      }                                                                    \
    }                                                                      \
  }
#define LOAD_W(kc_)                                                        \
  {                                                                        \
    _Pragma("unroll") for (int it = 0; it < 4; ++it)                       \
        wreg[it] = *(const short8*)(wt + (size_t)(kc_)*8192 + (it * 256 + tid) * 8); \
  }
#define WRITE_A(buf_)                                                      \
  {                                                                        \
    _Pragma("unroll") for (int j = 0; j < 2; ++j) {                        \
      const int slot = s0 + j;                                             \
      short8 s;                                                            \
      s[0] = f2bf(ar[j * 2].x); s[1] = f2bf(ar[j * 2].y);                  \
      s[2] = f2bf(ar[j * 2].z); s[3] = f2bf(ar[j * 2].w);                  \
      s[4] = f2bf(ar[j * 2 + 1].x); s[5] = f2bf(ar[j * 2 + 1].y);          \
      s[6] = f2bf(ar[j * 2 + 1].z); s[7] = f2bf(ar[j * 2 + 1].w);          \
      *(short8*)&Al[buf_][arow * 64 + ((slot ^ aswz) << 3)] = s;           \
    }                                                                      \
  }
#define WRITE_W(buf_)                                                      \
  {                                                                        \
    _Pragma("unroll") for (int it = 0; it < 4; ++it)                       \
        *(short8*)&Wl[buf_][(it * 256 + tid) * 8] = wreg[it];              \
  }

  LOAD_W(0) LOAD_A(0)
  WRITE_A(0) WRITE_W(0)
  __syncthreads();

  for (int t = 0; t < nkc; ++t) {
    const int cur = t & 1, nxt = cur ^ 1;
    const bool more = (t + 1 < nkc);
    if (more) { LOAD_W(t + 1) LOAD_A(t + 1) }
#pragma unroll
    for (int ks = 0; ks < 2; ++ks) {
      short8 af[2], wf[4];
#pragma unroll
      for (int i = 0; i < 2; ++i) {
        const int row = wr * 32 + i * 16 + (lane & 15);
        const int sa = (ks * 4 + (lane >> 4)) ^ (row & 7);
        af[i] = *(const short8*)&Al[cur][row * 64 + sa * 8];
      }
#pragma unroll
      for (int j = 0; j < 4; ++j) {
        const int col = wc * 64 + j * 16 + (lane & 15);
        const int sw2 = (ks * 4 + (lane >> 4)) ^ (col & 7);
        wf[j] = *(const short8*)&Wl[cur][col * 64 + sw2 * 8];
      }
#pragma unroll
      for (int i = 0; i < 2; ++i)
#pragma unroll
        for (int j = 0; j < 4; ++j)
          acc[i][j] = __builtin_amdgcn_mfma_f32_16x16x32_bf16(af[i], wf[j], acc[i][j], 0, 0, 0);
    }
    if (more) { WRITE_A(nxt) WRITE_W(nxt) }
    __syncthreads();
  }
#undef LOAD_A
#undef LOAD_W
#undef WRITE_A
#undef WRITE_W

  if (ksn > 1) {
#pragma unroll
    for (int i = 0; i < 2; ++i) {
      const int gm0 = bm + wr * 32 + i * 16 + (lane >> 4) * 4;
#pragma unroll
      for (int r = 0; r < 4; ++r) {
        const int gm = gm0 + r;
        if (gm >= M) continue;
#pragma unroll
        for (int j = 0; j < 4; ++j) {
          const int gn = bn + wc * 64 + j * 16 + (lane & 15);
          part[((size_t)kidx * M + gm) * ldc + gn] = acc[i][j][r];
        }
      }
    }
    return;
  }

  float br[4][8];
  if (LT) {
#pragma unroll
    for (int j = 0; j < 4; ++j) {
      const int gn = bn + wc * 64 + j * 16 + (lane & 15);
      const float4 u0 = *(const float4*)(Bz + (size_t)gn * 8);
      const float4 u1 = *(const float4*)(Bz + (size_t)gn * 8 + 4);
      br[j][0] = u0.x; br[j][1] = u0.y; br[j][2] = u0.z; br[j][3] = u0.w;
      br[j][4] = u1.x; br[j][5] = u1.y; br[j][6] = u1.z; br[j][7] = u1.w;
    }
  }
#pragma unroll
  for (int i = 0; i < 2; ++i) {
    const int gm0 = bm + wr * 32 + i * 16 + (lane >> 4) * 4;
#pragma unroll
    for (int r = 0; r < 4; ++r) {
      const int gm = gm0 + r;
      if (gm >= M) continue;
      float lt[8];
      if (LT) {
        const float4 t0 = *(const float4*)(LT + ((size_t)z * NTOK + gm) * 8);
        const float4 t1 = *(const float4*)(LT + ((size_t)z * NTOK + gm) * 8 + 4);
        lt[0] = t0.x; lt[1] = t0.y; lt[2] = t0.z; lt[3] = t0.w;
        lt[4] = t1.x; lt[5] = t1.y; lt[6] = t1.z; lt[7] = t1.w;
      }
#pragma unroll
      for (int j = 0; j < 4; ++j) {
        const int gn = bn + wc * 64 + j * 16 + (lane & 15);
        float o = acc[i][j][r] + bias[gn];
        if (LT)
          o += lt[0] * br[j][0] + lt[1] * br[j][1] + lt[2] * br[j][2] + lt[3] * br[j][3] +
               lt[4] * br[j][4] + lt[5] * br[j][5] + lt[6] * br[j][6] + lt[7] * br[j][7];
        const size_t off = (size_t)gm * ldc + gn;
        if (acc_flag) o += C[off];
        if (gelu_flag) o = gelu_f(o);
        C[off] = o;
      }
    }
  }
}

// Generic K-split reduce: X += sum_{h<KS}(part_h) + bias + LT@B^T  (N=1024)
__global__ __launch_bounds__(256) void reduce_ks(const float* __restrict__ part,
                                                 const float* __restrict__ bias,
                                                 const float* __restrict__ LT,
                                                 const float* __restrict__ Bm,
                                                 float* __restrict__ X, int KS) {
  const int idx = blockIdx.x * 256 + threadIdx.x;
  if (idx >= NTOK * 1024) return;
  const int gm = idx >> 10, gn = idx & 1023;
  float s = 0.f;
  for (int h = 0; h < KS; ++h) s += part[(size_t)h * NTOK * 1024 + idx];
  const float* t = LT + (size_t)gm * 8;
  const float* bp = Bm + (size_t)gn * 8;
  s += t[0] * bp[0] + t[1] * bp[1] + t[2] * bp[2] + t[3] * bp[3] +
       t[4] * bp[4] + t[5] * bp[5] + t[6] * bp[6] + t[7] * bp[7];
  X[idx] += s + bias[gn];
}

// ============ small-M fp32 GEMM v2 (M=32) with K-split ==========================
__global__ __launch_bounds__(256) void gemm_sm2(const float* __restrict__ A, int lda,
                                                const float* __restrict__ W, int ldw,
                                                const float* __restrict__ bias,
                                                float* __restrict__ C, int ldc,
                                                float* __restrict__ part,
                                                int N, int K, int gelu_flag) {
  __shared__ float buf[8192];
  const int tid = threadIdx.x;
  const int col = tid >> 3, ksub = tid & 7;
  const int gcol = blockIdx.x * 32 + col;
  const int KS = gridDim.y, ky = blockIdx.y;
  const int kchunk = (((K + KS - 1) / KS) + 127) & ~127;
  const int kstart = ky * kchunk;
  const int kend = (kstart + kchunk < K) ? (kstart + kchunk) : K;
  const float* wp = W + (size_t)(gcol < N ? gcol : 0) * ldw;

  float acc[32];
#pragma unroll
  for (int m = 0; m < 32; ++m) acc[m] = 0.f;

  for (int kc = kstart; kc < kend; kc += 128) {
    __syncthreads();
#pragma unroll
    for (int q = 0; q < 4; ++q) {
      const int idx4 = q * 256 + tid;
      const int m = idx4 >> 5, j = (idx4 & 31) * 4;
      const int gk = kc + j;
      float4 v;
      if (gk + 3 < K) {
        v = *(const float4*)(A + (size_t)m * lda + gk);
      } else {
        v.x = (gk < K) ? A[(size_t)m * lda + gk] : 0.f;
        v.y = (gk + 1 < K) ? A[(size_t)m * lda + gk + 1] : 0.f;
        v.z = (gk + 2 < K) ? A[(size_t)m * lda + gk + 2] : 0.f;
        v.w = (gk + 3 < K) ? A[(size_t)m * lda + gk + 3] : 0.f;
      }
      *(float4*)&buf[m * 128 + j] = v;
    }
    __syncthreads();
#pragma unroll
    for (int kk = 0; kk < 4; ++kk) {
      const int j = kk * 32 + ksub * 4;
      const int gk = kc + j;
      float4 w4 = make_float4(0.f, 0.f, 0.f, 0.f);
      if (gcol < N && gk < K) {
        if (gk + 3 < K) {
          w4 = *(const float4*)(wp + gk);
        } else {
          w4.x = wp[gk];
          if (gk + 1 < K) w4.y = wp[gk + 1];
          if (gk + 2 < K) w4.z = wp[gk + 2];
        }
      }
#pragma unroll
      for (int m = 0; m < 32; ++m) {
        const float4 a4 = *(const float4*)&buf[m * 128 + j];
        acc[m] += a4.x * w4.x + a4.y * w4.y + a4.z * w4.z + a4.w * w4.w;
      }
    }
  }
  __syncthreads();
#pragma unroll
  for (int m = 0; m < 32; ++m) buf[m * 256 + ksub * 32 + col] = acc[m];
  __syncthreads();
#pragma unroll
  for (int g = 0; g < 4; ++g) {
    const int idx = g * 256 + tid;
    const int m = idx >> 5, c = idx & 31;
    float s = 0.f;
#pragma unroll
    for (int h = 0; h < 8; ++h) s += buf[m * 256 + h * 32 + c];
    const int gc = blockIdx.x * 32 + c;
    if (gc < N) {
      if (KS == 1) {
        float o = s + bias[gc];
        if (gelu_flag) o = gelu_f(o);
        C[(size_t)m * ldc + gc] = o;
      } else {
        part[((size_t)ky * 32 + m) * N + gc] = s;
      }
    }
  }
}

__global__ __launch_bounds__(256) void reduce_sm(const float* __restrict__ part,
                                                 const float* __restrict__ bias,
                                                 float* __restrict__ C, int ldc,
                                                 int N, int KS, int gelu_flag) {
  const int idx = blockIdx.x * 256 + threadIdx.x;
  if (idx >= 32 * N) return;
  const int m = idx / N, c = idx - m * N;
  float s = 0.f;
  for (int h = 0; h < KS; ++h) s += part[((size_t)h * 32 + m) * N + c];
  float o = s + bias[c];
  if (gelu_flag) o = gelu_f(o);
  C[(size_t)m * ldc + c] = o;
}

// ============ sims ==============================================================
__global__ __launch_bounds__(256) void sims_kernel(const float* __restrict__ cur,
                                                   const float* __restrict__ bank,
                                                   float* __restrict__ sims) {
  __shared__ float Bs[32][132];
  __shared__ float Cs[32][36];
  const int tid = threadIdx.x;
  const int tx = tid & 7;
  const int ty = tid >> 3;
  const int n0 = blockIdx.x * 128;
  const int srow = tid >> 1;
  const int spart = tid & 1;
  const int cb = tid >> 3;
  const int ck = (tid & 7) * 4;

  float acc[4][4] = {{0.f,0.f,0.f,0.f},{0.f,0.f,0.f,0.f},
                     {0.f,0.f,0.f,0.f},{0.f,0.f,0.f,0.f}};

  const bool rok = (n0 + srow) < NB;
  const float* bp = bank + (size_t)(n0 + srow) * 768 + spart * 16;
  const float* cp = cur + (size_t)cb * 768 + ck;

  for (int kc = 0; kc < 768; kc += 32) {
    __syncthreads();
#pragma unroll
    for (int jj = 0; jj < 4; ++jj) {
      float4 v = rok ? *(const float4*)(bp + kc + jj * 4)
                     : make_float4(0.f, 0.f, 0.f, 0.f);
      const int kk = spart * 16 + jj * 4;
      Bs[kk + 0][srow] = v.x; Bs[kk + 1][srow] = v.y;
      Bs[kk + 2][srow] = v.z; Bs[kk + 3][srow] = v.w;
    }
    {
      float4 v = *(const float4*)(cp + kc);
      Cs[ck + 0][cb] = v.x; Cs[ck + 1][cb] = v.y;
      Cs[ck + 2][cb] = v.z; Cs[ck + 3][cb] = v.w;
    }
    __syncthreads();
#pragma unroll
    for (int kk = 0; kk < 32; ++kk) {
      float4 av = *(const float4*)&Bs[kk][ty * 4];
      float4 bv = *(const float4*)&Cs[kk][tx * 4];
      float a4[4] = {av.x, av.y, av.z, av.w};
      float b4[4] = {bv.x, bv.y, bv.z, bv.w};
#pragma unroll
      for (int i = 0; i < 4; ++i)
#pragma unroll
        for (int j = 0; j < 4; ++j) acc[i][j] += a4[i] * b4[j];
    }
  }
  const int n = n0 + ty * 4;
#pragma unroll
  for (int j = 0; j < 4; ++j) {
    const int b = tx * 4 + j;
    float4 o = make_float4(acc[0][j], acc[1][j], acc[2][j], acc[3][j]);
    if (n + 3 < NB) {
      *(float4*)(sims + (size_t)b * NB + n) = o;
    } else {
      float oo[4] = {o.x, o.y, o.z, o.w};
      for (int i = 0; i < 4; ++i)
        if (n + i < NB) sims[(size_t)b * NB + n + i] = oo[i];
    }
  }
}

// ===================== top-K ====================================================
__global__ __launch_bounds__(256) void topk_stage1(const float* __restrict__ sims,
                                                   float* __restrict__ cv,
                                                   int* __restrict__ ci) {
  __shared__ float ss[4096];
  __shared__ int si[4096];
  __shared__ float wv[4];
  __shared__ int wi[4];
  const int chunk = blockIdx.x, b = blockIdx.y, tid = threadIdx.x;
  const int start = chunk * (NB / TKCH), end = start + (NB / TKCH);
  float ls[16]; int li[16];
#pragma unroll
  for (int i = 0; i < 16; ++i) { ls[i] = -FLT_MAX; li[i] = 0x7fffffff; }
  const float* row = sims + (size_t)b * NB;
  float lmin = -FLT_MAX;
  for (int n = start + tid; n < end; n += 256) {
    float v = row[n];
    if (v > lmin) {
      int p = 15;
      while (p > 0 && ls[p - 1] < v) { ls[p] = ls[p - 1]; li[p] = li[p - 1]; --p; }
      ls[p] = v; li[p] = n;
      lmin = ls[15];
    }
  }
#pragma unroll
  for (int i = 0; i < 16; ++i) { ss[i * 256 + tid] = ls[i]; si[i * 256 + tid] = li[i]; }
  __syncthreads();
  for (int round = 0; round < 16; ++round) {
    float bv = -FLT_MAX; int bi = 0x7fffffff;
#pragma unroll
    for (int i = 0; i < 16; ++i) {
      float v = ss[i * 256 + tid]; int ix = si[i * 256 + tid];
      if (v > bv || (v == bv && ix < bi)) { bv = v; bi = ix; }
    }
#pragma unroll
    for (int s = 32; s; s >>= 1) {
      float ov = __shfl_down(bv, s); int oi = __shfl_down(bi, s);
      if (ov > bv || (ov == bv && oi < bi)) { bv = ov; bi = oi; }
    }
    if ((tid & 63) == 0) { wv[tid >> 6] = bv; wi[tid >> 6] = bi; }
    __syncthreads();
    if (tid == 0) {
      bv = wv[0]; bi = wi[0];
      for (int w = 1; w < 4; ++w)
        if (wv[w] > bv || (wv[w] == bv && wi[w] < bi)) { bv = wv[w]; bi = wi[w]; }
      cv[(b * TKCH + chunk) * 16 + round] = bv;
      ci[(b * TKCH + chunk) * 16 + round] = bi;
      wi[0] = bi;
    }
    __syncthreads();
    bi = wi[0];
#pragma unroll
    for (int i = 0; i < 16; ++i)
      if (si[i * 256 + tid] == bi) ss[i * 256 + tid] = -FLT_MAX;
    __syncthreads();
  }
}

__global__ __launch_bounds__(256) void topk_stage2(const float* __restrict__ cv,
                                                   const int* __restrict__ ci,
                                                   float* __restrict__ tks,
                                                   int* __restrict__ tki) {
  __shared__ float wv[4];
  __shared__ int wi[4];
  __shared__ int bw;
  const int b = blockIdx.x, tid = threadIdx.x;
  float val = cv[b * 256 + tid];
  int idx = ci[b * 256 + tid];
  for (int round = 0; round < 16; ++round) {
    float bv = val; int bi = idx;
#pragma unroll
    for (int s = 1; s < 64; s <<= 1) {
      float ov = __shfl_xor(bv, s); int oi = __shfl_xor(bi, s);
      if (ov > bv || (ov == bv && oi < bi)) { bv = ov; bi = oi; }
    }
    if ((tid & 63) == 0) { wv[tid >> 6] = bv; wi[tid >> 6] = bi; }
    __syncthreads();
    if (tid == 0) {
      bv = wv[0]; bi = wi[0];
      for (int w = 1; w < 4; ++w)
        if (wv[w] > bv || (wv[w] == bv && wi[w] < bi)) { bv = wv[w]; bi = wi[w]; }
      tks[b * 16 + round] = bv; tki[b * 16 + round] = bi;
      bw = bi;
    }
    __syncthreads();
    if (idx == bw) val = -FLT_MAX;
  }
}

// ===================== small copy/assembly kernels ==============================
__global__ void sem_kernel(const float* __restrict__ bank, const float* __restrict__ tks,
                           const int* __restrict__ tki, float* __restrict__ sem) {
  int slot = blockIdx.x;
  float s = tks[slot]; int idx = tki[slot];
  for (int i = threadIdx.x; i < 768; i += 256)
    sem[(size_t)slot * 768 + i] = bank[(size_t)idx * 768 + i] * s;
}

// HIN stride 832, zero-padded k>=777
__global__ void build_hist_in(const float* __restrict__ img, const float* __restrict__ pr,
                              float* __restrict__ out) {
  int r = blockIdx.x;
  for (int i = threadIdx.x; i < 832; i += 256)
    out[(size_t)r * 832 + i] = (i < 768) ? img[(size_t)r * 768 + i]
                             : (i < 777) ? pr[r * 9 + (i - 768)] : 0.f;
}

__global__ void build_img_in(const float* __restrict__ goal, const float* __restrict__ sub,
                             const float* __restrict__ bea, const float* __restrict__ sem,
                             float* __restrict__ out) {
  int r = blockIdx.x;
  const float* src = (r < 32) ? goal + (size_t)r * 768
                   : (r < 64) ? sub + (size_t)(r - 32) * 768
                   : (r < 96) ? bea + (size_t)(r - 64) * 768
                              : sem + (size_t)(r - 96) * 768;
  for (int i = threadIdx.x; i < 768; i += 256) out[(size_t)r * 768 + i] = src[i];
}

__global__ void assemble_x(const float* __restrict__ th, const float* __restrict__ ti,
                           const float* __restrict__ tp, const float* __restrict__ plan,
                           float* __restrict__ x) {
  int r = blockIdx.x;
  int b = r / SEQ, tok = r - b * SEQ;
  const float* src;
  if (tok == 0) src = plan;
  else if (tok <= 16) src = th + (size_t)(b * 16 + tok - 1) * 1024;
  else if (tok <= 19) src = ti + (size_t)((tok - 17) * 32 + b) * 1024;
  else if (tok <= 35) src = ti + (size_t)(96 + b * 16 + (tok - 20)) * 1024;
  else src = tp + (size_t)b * 1024;
  for (int i = threadIdx.x; i < 1024; i += 256) x[(size_t)r * 1024 + i] = src[i];
}

__global__ void build_ref(const float* __restrict__ ps, const float* __restrict__ anc,
                          float* __restrict__ ref) {
  int b = blockIdx.x;
  for (int i = threadIdx.x; i < 1027; i += 256)
    ref[(size_t)b * 1027 + i] = (i < 1024) ? ps[(size_t)b * 1024 + i] : anc[b * 3 + (i - 1024)];
}

// ===================== layernorm (+fused LoRA-down, nz matrices) ===============
__device__ __forceinline__ float block_sum256(float v, float* red) {
#pragma unroll
  for (int s = 32; s; s >>= 1) v += __shfl_down(v, s);
  if ((threadIdx.x & 63) == 0) red[threadIdx.x >> 6] = v;
  __syncthreads();
  float tot = red[0] + red[1] + red[2] + red[3];
  __syncthreads();
  return tot;
}

__global__ __launch_bounds__(256) void ln_kernel(const float* __restrict__ in, int in_stride,
                                                 float* __restrict__ out,
                                                 const float* __restrict__ g,
                                                 const float* __restrict__ bt,
                                                 const float* __restrict__ A0,
                                                 const float* __restrict__ A1,
                                                 const float* __restrict__ A2,
                                                 int nz, float* __restrict__ lt) {
  __shared__ float red[4];
  __shared__ float red2[4][8];
  const float* xr = in + (size_t)blockIdx.x * in_stride;
  const int tid = threadIdx.x;
  const int wave = tid >> 6, lane = tid & 63;
  float v[4];
#pragma unroll
  for (int i = 0; i < 4; ++i) v[i] = xr[tid + 256 * i];
  float mean = block_sum256(v[0] + v[1] + v[2] + v[3], red) * (1.f / 1024.f);
  float sq = 0.f;
#pragma unroll
  for (int i = 0; i < 4; ++i) { float d = v[i] - mean; sq += d * d; }
  float var = block_sum256(sq, red) * (1.f / 1024.f);
  float inv = rsqrtf(var + 1e-5f);
  float* orow = out + (size_t)blockIdx.x * 1024;
  float nv[4];
#pragma unroll
  for (int i = 0; i < 4; ++i) {
    int c = tid + 256 * i;
    nv[i] = (v[i] - mean) * inv * g[c] + bt[c];
    orow[c] = nv[i];
  }
  for (int z = 0; z < nz; ++z) {
    const float* Am = (z == 0) ? A0 : (z == 1) ? A1 : A2;
    float p[8];
#pragma unroll
    for (int r = 0; r < 8; ++r) {
      float s = 0.f;
#pragma unroll
      for (int i = 0; i < 4; ++i) s += nv[i] * Am[r * 1024 + tid + 256 * i];
      p[r] = s;
    }
#pragma unroll
    for (int sh = 1; sh < 64; sh <<= 1) {
#pragma unroll
      for (int r = 0; r < 8; ++r) p[r] += __shfl_xor(p[r], sh);
    }
    if (lane == 0) {
#pragma unroll
      for (int r = 0; r < 8; ++r) red2[wave][r] = p[r];
    }
    __syncthreads();
    if (tid < 8)
      lt[((size_t)z * NTOK + blockIdx.x) * 8 + tid] =
          red2[0][tid] + red2[1][tid] + red2[2][tid] + red2[3][tid];
    __syncthreads();
  }
}

// ===================== LoRA down (standalone, for o/f2 inputs) ==================
__global__ __launch_bounds__(256) void lora_down(const float* __restrict__ h,
                                                 const float* __restrict__ A0,
                                                 const float* __restrict__ A1,
                                                 const float* __restrict__ A2,
                                                 float* __restrict__ lt, int K) {
  __shared__ float red[4][8];
  const int m = blockIdx.x, z = blockIdx.y;
  const int tid = threadIdx.x, wave = tid >> 6, lane = tid & 63;
  const float* A = (z == 0) ? A0 : (z == 1) ? A1 : A2;
  float p[8] = {0.f, 0.f, 0.f, 0.f, 0.f, 0.f, 0.f, 0.f};
  for (int kk = tid; kk < K; kk += 256) {
    float hv = h[(size_t)m * K + kk];
#pragma unroll
    for (int r = 0; r < 8; ++r) p[r] += hv * A[r * K + kk];
  }
#pragma unroll
  for (int s = 1; s < 64; s <<= 1) {
#pragma unroll
    for (int r = 0; r < 8; ++r) p[r] += __shfl_xor(p[r], s);
  }
  if (lane == 0) {
#pragma unroll
    for (int r = 0; r < 8; ++r) red[wave][r] = p[r];
  }
  __syncthreads();
  if (tid < 8)
    lt[((size_t)z * NTOK + m) * 8 + tid] =
        red[0][tid] + red[1][tid] + red[2][tid] + red[3][tid];
}

// ===================== attention ================================================
__global__ __launch_bounds__(256) void attn_kernel(const float* __restrict__ q,
                                                   const float* __restrict__ k,
                                                   const float* __restrict__ v,
                                                   float* __restrict__ ao) {
  __shared__ float qs[SEQ * 64], ks[SEQ * 64], vs[SEQ * 64], sc[SEQ * 40];
  const int head = blockIdx.x, b = blockIdx.y, tid = threadIdx.x;
  const size_t base = ((size_t)b * SEQ) * 1024 + head * 64;
  for (int i = tid; i < SEQ * 64; i += 256) {
    int s = i >> 6, d = i & 63;
    size_t off = base + (size_t)s * 1024 + d;
    qs[i] = q[off]; ks[i] = k[off]; vs[i] = v[off];
  }
  __syncthreads();
  for (int p = tid; p < SEQ * SEQ; p += 256) {
    int s = p / SEQ, t = p - s * SEQ;
    float acc = 0.f;
#pragma unroll 16
    for (int d = 0; d < 64; ++d) acc += qs[s * 64 + d] * ks[t * 64 + d];
    sc[s * 40 + t] = acc * 0.125f;
  }
  __syncthreads();
  if (tid < SEQ) {
    float m = -FLT_MAX;
    for (int t = 0; t < SEQ; ++t) m = fmaxf(m, sc[tid * 40 + t]);
    float sum = 0.f;
    for (int t = 0; t < SEQ; ++t) { float e = expf(sc[tid * 40 + t] - m); sc[tid * 40 + t] = e; sum += e; }
    float inv = 1.f / sum;
    for (int t = 0; t < SEQ; ++t) sc[tid * 40 + t] *= inv;
  }
  __syncthreads();
  for (int i = tid; i < SEQ * 64; i += 256) {
    int s = i >> 6, d = i & 63;
    float acc = 0.f;
    for (int t = 0; t < SEQ; ++t) acc += sc[s * 40 + t] * vs[t * 64 + d];
    ao[base + (size_t)s * 1024 + d] = acc;
  }
}

// ===================== host =====================================================
extern "C" void kernel_launch(void* const* d_in, const int* in_sizes, int n_in,
                              void* d_out, int out_size, void* d_ws, size_t ws_size,
                              hipStream_t stream) {
  const float* hist_img = (const float*)d_in[0];
  const float* cur      = (const float*)d_in[1];
  const float* goal     = (const float*)d_in[2];
  const float* sub      = (const float*)d_in[3];
  const float* bea      = (const float*)d_in[4];
  const float* hist_pr  = (const float*)d_in[5];
  const float* prop     = (const float*)d_in[6];
  const float* bank     = (const float*)d_in[7];
  const float* hpW = (const float*)d_in[8];  const float* hpb = (const float*)d_in[9];
  const float* ipW = (const float*)d_in[10]; const float* ipb = (const float*)d_in[11];
  const float* ppW = (const float*)d_in[12]; const float* ppb = (const float*)d_in[13];
  const float* plan = (const float*)d_in[14];
  const float* ln1g = (const float*)d_in[15]; const float* ln1b = (const float*)d_in[16];
  const float* ln2g = (const float*)d_in[17]; const float* ln2b = (const float*)d_in[18];
  const float* qW = (const float*)d_in[19]; const float* qA = (const float*)d_in[20];
  const float* qB = (const float*)d_in[21]; const float* qb = (const float*)d_in[22];
  const float* kW = (const float*)d_in[23]; const float* kA = (const float*)d_in[24];
  const float* kB = (const float*)d_in[25]; const float* kb = (const float*)d_in[26];
  const float* vW = (const float*)d_in[27]; const float* vA = (const float*)d_in[28];
  const float* vB = (const float*)d_in[29]; const float* vb = (const float*)d_in[30];
  const float* oW = (const float*)d_in[31]; const float* oA = (const float*)d_in[32];
  const float* oB = (const float*)d_in[33]; const float* ob = (const float*)d_in[34];
  const float* f1W = (const float*)d_in[35]; const float* f1A = (const float*)d_in[36];
  const float* f1B = (const float*)d_in[37]; const float* f1b = (const float*)d_in[38];
  const float* f2W = (const float*)d_in[39]; const float* f2A = (const float*)d_in[40];
  const float* f2B = (const float*)d_in[41]; const float* f2b = (const float*)d_in[42];
  const float* flng = (const float*)d_in[43]; const float* flnb = (const float*)d_in[44];
  const float* ahW1 = (const float*)d_in[45]; const float* ahb1 = (const float*)d_in[46];
  const float* ahW2 = (const float*)d_in[47]; const float* ahb2 = (const float*)d_in[48];
  const float* rhW1 = (const float*)d_in[49]; const float* rhb1 = (const float*)d_in[50];
  const float* rhW2 = (const float*)d_in[51]; const float* rhb2 = (const float*)d_in[52];
  const float* shW = (const float*)d_in[53]; const float* shb = (const float*)d_in[54];
  float* out = (float*)d_out;

  float* ws  = (float*)d_ws;
  float* F1O = ws;
  float* SIMS = ws;
  float* X   = F1O + (size_t)NTOK * 4096;
  float* Hb  = X  + (size_t)NTOK * 1024;
  float* Qb  = Hb + (size_t)NTOK * 1024;
  float* Kb  = Qb + (size_t)NTOK * 1024;
  float* Vb  = Kb + (size_t)NTOK * 1024;
  float* AOb = Vb + (size_t)NTOK * 1024;
  float* LT  = AOb + (size_t)NTOK * 1024;      // 3*NTOK*8
  float* SEM = LT + (size_t)3 * NTOK * 8;
  float* HIN = SEM + (size_t)512 * 768;        // 512*832 (padded)
  float* TKS = HIN + (size_t)512 * 832;
  int*   TKI = (int*)(TKS + 512);
  float* PS  = TKS + 1024;
  float* HH  = PS + 32 * 1024;
  float* REF = HH + 32 * 1024;
  float* CV  = REF + 32 * 1027;
  int*   CI  = (int*)(CV + 32 * 256);
  float* PART = (float*)(CI + 32 * 256);       // heads: 8*32*1024
  float* PF2 = PART + 8 * 32 * 1024;           // K-split partials: 4*NTOK*1024
  short* WB  = (short*)(PF2 + (size_t)4 * NTOK * 1024);  // 6*12M shorts
  short* WBE = WB + (size_t)6 * 12 * 1048576;  // embed: 200*8192 shorts

  const size_t czs = (size_t)NTOK * 1024;
  const size_t WM = 1048576;
  const size_t WL = 12 * WM;

  auto gemms = [&](const float* A, int lda, const float* W, int ldw, const float* bias,
                   float* C, int ldc, int N, int K, int geluf, int KS) {
    gemm_sm2<<<dim3((N + 31) / 32, KS), 256, 0, stream>>>(A, lda, W, ldw, bias,
                                                          C, ldc, PART, N, K, geluf);
    if (KS > 1)
      reduce_sm<<<(32 * N + 255) / 256, 256, 0, stream>>>(PART, bias, C, ldc, N, KS, geluf);
  };

  // ---- weight conversions ----
  wconv_all<<<6 * 1536, 256, 0, stream>>>(qW, kW, vW, oW, f1W, f2W, WB);
  wconv_embed<<<200, 256, 0, stream>>>(hpW, ipW, WBE);

  // ---- retrieval ----
  sims_kernel<<<(NB + 127) / 128, 256, 0, stream>>>(cur, bank, SIMS);
  topk_stage1<<<dim3(TKCH, 32), 256, 0, stream>>>(SIMS, CV, CI);
  topk_stage2<<<32, 256, 0, stream>>>(CV, CI, TKS, TKI);
  sem_kernel<<<512, 256, 0, stream>>>(bank, TKS, TKI, SEM);

  // ---- token embedding (tiled bf16 GEMMs) ----
  build_hist_in<<<512, 256, 0, stream>>>(hist_img, hist_pr, HIN);
  build_img_in<<<608, 256, 0, stream>>>(goal, sub, bea, SEM, AOb);
  gemm_bt<<<dim3(8, 8, 1), 256, 0, stream>>>(
      HIN, 832, WBE, 0, hpb, hpb, hpb,
      nullptr, nullptr, nullptr, nullptr, Qb, 0, 1024, 512, 832, 0, 0, 1, nullptr);
  gemm_bt<<<dim3(10, 8, 1), 256, 0, stream>>>(
      AOb, 768, WBE + (size_t)104 * 8192, 0, ipb, ipb, ipb,
      nullptr, nullptr, nullptr, nullptr, Kb, 0, 1024, 608, 768, 0, 0, 1, nullptr);
  gemms(prop, 9, ppW, 9, ppb, Vb, 1024, 1024, 9, 0, 1);
  assemble_x<<<NTOK, 256, 0, stream>>>(Qb, Kb, Vb, plan, X);

  // ---- transformer layers ----
  const int mblk = (NTOK + 63) / 64;  // 19
  for (int l = 0; l < 6; ++l) {
    const size_t aO = (size_t)l * 8 * 1024, bO = (size_t)l * 1024 * 8,
                 biO = (size_t)l * 1024;
    const size_t a4O = (size_t)l * 8 * 4096, b4O = (size_t)l * 4096 * 8,
                 bi4O = (size_t)l * 4096;
    const short* WBl = WB + (size_t)l * WL;
    // ln1 + fused qkv lora-down
    ln_kernel<<<NTOK, 256, 0, stream>>>(X, 1024, Hb, ln1g + biO, ln1b + biO,
                                        qA + aO, kA + aO, vA + aO, 3, LT);
    gemm_bt<<<dim3(mblk, 8, 3), 256, 0, stream>>>(
        Hb, 1024, WBl, WM, qb + biO, kb + biO, vb + biO,
        LT, qB + bO, kB + bO, vB + bO, Qb, czs, 1024, NTOK, 1024, 0, 0, 1, nullptr);
    attn_kernel<<<dim3(16, 32), 256, 0, stream>>>(Qb, Kb, Vb, AOb);
    lora_down<<<dim3(NTOK, 1), 256, 0, stream>>>(AOb, oA + aO, oA + aO, oA + aO, LT, 1024);
    gemm_bt<<<dim3(mblk, 8, 2), 256, 0, stream>>>(        // o: K-split x2
        AOb, 1024, WBl + 3 * WM, 0, ob + biO, ob + biO, ob + biO,
        nullptr, nullptr, nullptr, nullptr, nullptr, 0, 1024, NTOK, 1024, 0, 0, 2, PF2);
    reduce_ks<<<(NTOK * 1024 + 255) / 256, 256, 0, stream>>>(PF2, ob + biO, LT,
                                                             oB + bO, X, 2);
    // ln2 + fused f1 lora-down
    ln_kernel<<<NTOK, 256, 0, stream>>>(X, 1024, Hb, ln2g + biO, ln2b + biO,
                                        f1A + aO, f1A + aO, f1A + aO, 1, LT);
    gemm_bt<<<dim3(mblk, 32, 1), 256, 0, stream>>>(
        Hb, 1024, WBl + 4 * WM, 0, f1b + bi4O, f1b + bi4O, f1b + bi4O,
        LT, f1B + b4O, f1B + b4O, f1B + b4O, F1O, 0, 4096, NTOK, 1024, 0, 1, 1, nullptr);
    lora_down<<<dim3(NTOK, 1), 256, 0, stream>>>(F1O, f2A + a4O, f2A + a4O, f2A + a4O, LT, 4096);
    gemm_bt<<<dim3(mblk, 8, 4), 256, 0, stream>>>(        // f2: K-split x4
        F1O, 4096, WBl + 8 * WM, 0, f2b + biO, f2b + biO, f2b + biO,
        nullptr, nullptr, nullptr, nullptr, nullptr, 0, 1024, NTOK, 4096, 0, 0, 4, PF2);
    reduce_ks<<<(NTOK * 1024 + 255) / 256, 256, 0, stream>>>(PF2, f2b + biO, LT,
                                                             f2B + bO, X, 4);
  }

  // ---- heads ----
  ln_kernel<<<32, 256, 0, stream>>>(X, SEQ * 1024, PS, flng, flnb,
                                    nullptr, nullptr, nullptr, 0, nullptr);
  gemms(PS, 1024, ahW1, 1024, ahb1, HH, 1024, 1024, 1024, 1, 8);
  gemms(HH, 1024, ahW2, 1024, ahb2, out, 3, 3, 1024, 0, 8);
  build_ref<<<32, 256, 0, stream>>>(PS, out, REF);
  gemms(REF, 1027, rhW1, 1027, rhb1, HH, 1024, 1024, 1027, 1, 8);
  gemms(HH, 1024, rhW2, 1024, rhb2, out + 96, 24, 24, 1024, 0, 8);
  gemms(PS, 1024, shW, 1024, shb, out + 864, 1, 1, 1024, 0, 8);
}

// Round 13
// 1687.993 us; speedup vs baseline: 1.4319x; 1.0027x over previous
//
#include <hip/hip_runtime.h>
#include <float.h>
#include <math.h>

#define NB 100000
#define SEQ 37
#define NTOK 1184  // 32*37
#define TKCH 16

typedef __attribute__((ext_vector_type(8))) short short8;
typedef __attribute__((ext_vector_type(4))) float floatx4;

__device__ __forceinline__ short f2bf(float f) {
  union { float f; unsigned u; } x; x.f = f;
  unsigned r = x.u + 0x7fff + ((x.u >> 16) & 1);  // RNE
  return (short)(r >> 16);
}

__device__ __forceinline__ float gelu_f(float v) {
  return 0.5f * v * (1.f + erff(v * 0.70710678118654752f));
}

// ===================== all-layer weight conversion ==============================
__global__ __launch_bounds__(256) void wconv_all(const float* __restrict__ qW,
                                                 const float* __restrict__ kW,
                                                 const float* __restrict__ vW,
                                                 const float* __restrict__ oW,
                                                 const float* __restrict__ f1W,
                                                 const float* __restrict__ f2W,
                                                 short* __restrict__ wb) {
  const int l = blockIdx.x / 1536;
  const int t = blockIdx.x - l * 1536;
  const float* src; int Kd; size_t doff; int np, kc;
  if (t < 512) {
    const int w = t >> 7, ti = t & 127;
    const float* base = (w == 0) ? qW : (w == 1) ? kW : (w == 2) ? vW : oW;
    src = base + (size_t)l * 1024 * 1024;
    Kd = 1024; np = ti >> 4; kc = ti & 15;
    doff = (size_t)w * 1048576 + ((size_t)np * 16 + kc) * 8192;
  } else if (t < 1024) {
    const int ti = t - 512;
    src = f1W + (size_t)l * 4096 * 1024;
    Kd = 1024; np = ti >> 4; kc = ti & 15;
    doff = (size_t)4 * 1048576 + ((size_t)np * 16 + kc) * 8192;
  } else {
    const int ti = t - 1024;
    src = f2W + (size_t)l * 1024 * 4096;
    Kd = 4096; np = ti >> 6; kc = ti & 63;
    doff = (size_t)8 * 1048576 + ((size_t)np * 64 + kc) * 8192;
  }
  short* dst = wb + (size_t)l * 12 * 1048576 + doff;
  const float* sp = src + (size_t)(np * 128) * Kd + kc * 64;
  const int tid = threadIdx.x;
#pragma unroll
  for (int q = 0; q < 4; ++q) {
    const int d = q * 256 + tid;
    const int row = d >> 3, slot = d & 7;
    const int ss = slot ^ (row & 7);
    const float* s = sp + (size_t)row * Kd + ss * 8;
    const float4 u0 = *(const float4*)s;
    const float4 u1 = *(const float4*)(s + 4);
    short8 v;
    v[0] = f2bf(u0.x); v[1] = f2bf(u0.y); v[2] = f2bf(u0.z); v[3] = f2bf(u0.w);
    v[4] = f2bf(u1.x); v[5] = f2bf(u1.y); v[6] = f2bf(u1.z); v[7] = f2bf(u1.w);
    *(short8*)(dst + (size_t)d * 8) = v;
  }
}

// ===================== embed weight conversion (hpW K=777->832, ipW K=768) =====
__global__ __launch_bounds__(256) void wconv_embed(const float* __restrict__ hpW,
                                                   const float* __restrict__ ipW,
                                                   short* __restrict__ wbe) {
  const int t = blockIdx.x;
  const float* src; int Kd, np, kc; size_t doff;
  if (t < 104) { src = hpW; Kd = 777; np = t / 13; kc = t - np * 13; doff = (size_t)t * 8192; }
  else { const int ti = t - 104; src = ipW; Kd = 768; np = ti / 12; kc = ti - np * 12;
         doff = (size_t)t * 8192; }
  short* dst = wbe + doff;
  const int tid = threadIdx.x;
#pragma unroll
  for (int q = 0; q < 4; ++q) {
    const int d = q * 256 + tid;
    const int row = d >> 3, slot = d & 7;
    const int ss = slot ^ (row & 7);
    const int gk0 = kc * 64 + ss * 8;
    const float* s = src + (size_t)(np * 128 + row) * Kd;
    short8 v;
#pragma unroll
    for (int e = 0; e < 8; ++e) v[e] = (gk0 + e < Kd) ? f2bf(s[gk0 + e]) : (short)0;
    *(short8*)(dst + (size_t)d * 8) = v;
  }
}

// ============ MFMA GEMM, bf16-tiled weights, fused LoRA/residual/gelu ==========
__global__ __launch_bounds__(256) void gemm_bt(const float* __restrict__ A, int lda,
                                               const short* __restrict__ WT, size_t wzstride,
                                               const float* __restrict__ b0,
                                               const float* __restrict__ b1,
                                               const float* __restrict__ b2,
                                               const float* __restrict__ LT,
                                               const float* __restrict__ B0,
                                               const float* __restrict__ B1,
                                               const float* __restrict__ B2,
                                               float* __restrict__ C, size_t czstride,
                                               int ldc, int M, int K,
                                               int acc_flag, int gelu_flag,
                                               int ksn, float* __restrict__ part) {
  __shared__ short Al[2][64 * 64];
  __shared__ short Wl[2][128 * 64];
  const int z = blockIdx.z;
  const int kidx = (ksn > 1) ? z : 0;
  const float* bias = (ksn > 1 || z == 0) ? b0 : (z == 1) ? b1 : b2;
  const float* Bz = (ksn > 1 || z == 0) ? B0 : (z == 1) ? B1 : B2;
  if (ksn == 1) C += (size_t)z * czstride;
  const int nkc_tot = K >> 6;
  const int nkc = nkc_tot / ksn;
  const short* wt = WT + (size_t)((ksn > 1) ? 0 : z) * wzstride +
                    ((size_t)blockIdx.y * nkc_tot + (size_t)kidx * nkc) * 8192;
  const int tid = threadIdx.x;
  const int wid = tid >> 6, lane = tid & 63;
  const int wr = wid >> 1, wc = wid & 1;
  const int bm = blockIdx.x * 64, bn = blockIdx.y * 128;
  const int arow = tid >> 2;
  const int s0 = (tid & 3) * 2;

  floatx4 acc[2][4];
#pragma unroll
  for (int i = 0; i < 2; ++i)
#pragma unroll
    for (int j = 0; j < 4; ++j)
#pragma unroll
      for (int r = 0; r < 4; ++r) acc[i][j][r] = 0.f;

  const int ga = bm + arow;
  const bool aok = ga < M;
  const float* ap = A + (size_t)ga * lda + (size_t)kidx * nkc * 64;
  const int aswz = arow & 7;

  float4 ar[4];
  short8 wreg[4];

#define LOAD_A(kc_)                                                        \
  {                                                                        \
    _Pragma("unroll") for (int j = 0; j < 2; ++j) {                        \
      const int slot = s0 + j;                                             \
      if (aok) {                                                           \
        ar[j * 2] = *(const float4*)(ap + (kc_)*64 + slot * 8);            \
        ar[j * 2 + 1] = *(const float4*)(ap + (kc_)*64 + slot * 8 + 4);    \
      } else {                                                             \
        ar[j * 2] = make_float4(0.f, 0.f, 0.f, 0.f);                      \
        ar[j * 2 + 1] = make_float4(0.f, 0.f, 0.f, 0.f);                  \
      }                                                                    \
    }                                                                      \
  }
#define LOAD_W(kc_)                                                        \
  {                                                                        \
    _Pragma("unroll") for (int it = 0; it < 4; ++it)                       \
        wreg[it] = *(const short8*)(wt + (size_t)(kc_)*8192 + (it * 256 + tid) * 8); \
  }
#define WRITE_A(buf_)                                                      \
  {                                                                        \
    _Pragma("unroll") for (int j = 0; j < 2; ++j) {                        \
      const int slot = s0 + j;                                             \
      short8 s;                                                            \
      s[0] = f2bf(ar[j * 2].x); s[1] = f2bf(ar[j * 2].y);                  \
      s[2] = f2bf(ar[j * 2].z); s[3] = f2bf(ar[j * 2].w);                  \
      s[4] = f2bf(ar[j * 2 + 1].x); s[5] = f2bf(ar[j * 2 + 1].y);          \
      s[6] = f2bf(ar[j * 2 + 1].z); s[7] = f2bf(ar[j * 2 + 1].w);          \
      *(short8*)&Al[buf_][arow * 64 + ((slot ^ aswz) << 3)] = s;           \
    }                                                                      \
  }
#define WRITE_W(buf_)                                                      \
  {                                                                        \
    _Pragma("unroll") for (int it = 0; it < 4; ++it)                       \
        *(short8*)&Wl[buf_][(it * 256 + tid) * 8] = wreg[it];              \
  }

  LOAD_W(0) LOAD_A(0)
  WRITE_A(0) WRITE_W(0)
  __syncthreads();

  for (int t = 0; t < nkc; ++t) {
    const int cur = t & 1, nxt = cur ^ 1;
    const bool more = (t + 1 < nkc);
    if (more) { LOAD_W(t + 1) LOAD_A(t + 1) }
#pragma unroll
    for (int ks = 0; ks < 2; ++ks) {
      short8 af[2], wf[4];
#pragma unroll
      for (int i = 0; i < 2; ++i) {
        const int row = wr * 32 + i * 16 + (lane & 15);
        const int sa = (ks * 4 + (lane >> 4)) ^ (row & 7);
        af[i] = *(const short8*)&Al[cur][row * 64 + sa * 8];
      }
#pragma unroll
      for (int j = 0; j < 4; ++j) {
        const int col = wc * 64 + j * 16 + (lane & 15);
        const int sw2 = (ks * 4 + (lane >> 4)) ^ (col & 7);
        wf[j] = *(const short8*)&Wl[cur][col * 64 + sw2 * 8];
      }
#pragma unroll
      for (int i = 0; i < 2; ++i)
#pragma unroll
        for (int j = 0; j < 4; ++j)
          acc[i][j] = __builtin_amdgcn_mfma_f32_16x16x32_bf16(af[i], wf[j], acc[i][j], 0, 0, 0);
    }
    if (more) { WRITE_A(nxt) WRITE_W(nxt) }
    __syncthreads();
  }
#undef LOAD_A
#undef LOAD_W
#undef WRITE_A
#undef WRITE_W

  if (ksn > 1) {
#pragma unroll
    for (int i = 0; i < 2; ++i) {
      const int gm0 = bm + wr * 32 + i * 16 + (lane >> 4) * 4;
#pragma unroll
      for (int r = 0; r < 4; ++r) {
        const int gm = gm0 + r;
        if (gm >= M) continue;
#pragma unroll
        for (int j = 0; j < 4; ++j) {
          const int gn = bn + wc * 64 + j * 16 + (lane & 15);
          part[((size_t)kidx * M + gm) * ldc + gn] = acc[i][j][r];
        }
      }
    }
    return;
  }

  float br[4][8];
  if (LT) {
#pragma unroll
    for (int j = 0; j < 4; ++j) {
      const int gn = bn + wc * 64 + j * 16 + (lane & 15);
      const float4 u0 = *(const float4*)(Bz + (size_t)gn * 8);
      const float4 u1 = *(const float4*)(Bz + (size_t)gn * 8 + 4);
      br[j][0] = u0.x; br[j][1] = u0.y; br[j][2] = u0.z; br[j][3] = u0.w;
      br[j][4] = u1.x; br[j][5] = u1.y; br[j][6] = u1.z; br[j][7] = u1.w;
    }
  }
#pragma unroll
  for (int i = 0; i < 2; ++i) {
    const int gm0 = bm + wr * 32 + i * 16 + (lane >> 4) * 4;
#pragma unroll
    for (int r = 0; r < 4; ++r) {
      const int gm = gm0 + r;
      if (gm >= M) continue;
      float lt[8];
      if (LT) {
        const float4 t0 = *(const float4*)(LT + ((size_t)z * NTOK + gm) * 8);
        const float4 t1 = *(const float4*)(LT + ((size_t)z * NTOK + gm) * 8 + 4);
        lt[0] = t0.x; lt[1] = t0.y; lt[2] = t0.z; lt[3] = t0.w;
        lt[4] = t1.x; lt[5] = t1.y; lt[6] = t1.z; lt[7] = t1.w;
      }
#pragma unroll
      for (int j = 0; j < 4; ++j) {
        const int gn = bn + wc * 64 + j * 16 + (lane & 15);
        float o = acc[i][j][r] + bias[gn];
        if (LT)
          o += lt[0] * br[j][0] + lt[1] * br[j][1] + lt[2] * br[j][2] + lt[3] * br[j][3] +
               lt[4] * br[j][4] + lt[5] * br[j][5] + lt[6] * br[j][6] + lt[7] * br[j][7];
        const size_t off = (size_t)gm * ldc + gn;
        if (acc_flag) o += C[off];
        if (gelu_flag) o = gelu_f(o);
        C[off] = o;
      }
    }
  }
}

// Generic K-split reduce (standalone, final layer): X += sum + bias + LT@B^T
__global__ __launch_bounds__(256) void reduce_ks(const float* __restrict__ part,
                                                 const float* __restrict__ bias,
                                                 const float* __restrict__ LT,
                                                 const float* __restrict__ Bm,
                                                 float* __restrict__ X, int KS) {
  const int idx = blockIdx.x * 256 + threadIdx.x;
  if (idx >= NTOK * 1024) return;
  const int gm = idx >> 10, gn = idx & 1023;
  float s = 0.f;
  for (int h = 0; h < KS; ++h) s += part[(size_t)h * NTOK * 1024 + idx];
  const float* t = LT + (size_t)gm * 8;
  const float* bp = Bm + (size_t)gn * 8;
  s += t[0] * bp[0] + t[1] * bp[1] + t[2] * bp[2] + t[3] * bp[3] +
       t[4] * bp[4] + t[5] * bp[5] + t[6] * bp[6] + t[7] * bp[7];
  X[idx] += s + bias[gn];
}

// ======= fused: K-split reduce + residual + LoRA-up  ->  LN -> LoRA-down =======
// One block per row. X[row] += sum(part)+bias+LT0@B^T; then LN(xnew)->out,
// then nz LoRA-down projections (A0..A2) -> lt (overwrites slot 0..nz-1; safe:
// this row's input LT is read into regs first).
__global__ __launch_bounds__(256) void redln(const float* __restrict__ part, int KS,
                                             const float* __restrict__ bias,
                                             const float* __restrict__ Bm,
                                             float* __restrict__ X,
                                             float* __restrict__ out,
                                             const float* __restrict__ g,
                                             const float* __restrict__ bt,
                                             const float* __restrict__ A0,
                                             const float* __restrict__ A1,
                                             const float* __restrict__ A2,
                                             int nz, float* __restrict__ lt) {
  __shared__ float red[4];
  __shared__ float red2[4][8];
  const int row = blockIdx.x, tid = threadIdx.x;
  const int wave = tid >> 6, lane = tid & 63;
  float ltv[8];
  {
    const float4 t0 = *(const float4*)(lt + (size_t)row * 8);
    const float4 t1 = *(const float4*)(lt + (size_t)row * 8 + 4);
    ltv[0] = t0.x; ltv[1] = t0.y; ltv[2] = t0.z; ltv[3] = t0.w;
    ltv[4] = t1.x; ltv[5] = t1.y; ltv[6] = t1.z; ltv[7] = t1.w;
  }
  float v[4];
#pragma unroll
  for (int i = 0; i < 4; ++i) {
    const int c = tid + 256 * i;
    float s = 0.f;
    for (int h = 0; h < KS; ++h)
      s += part[((size_t)h * NTOK + row) * 1024 + c];
    const float* bp = Bm + (size_t)c * 8;
    s += ltv[0] * bp[0] + ltv[1] * bp[1] + ltv[2] * bp[2] + ltv[3] * bp[3] +
         ltv[4] * bp[4] + ltv[5] * bp[5] + ltv[6] * bp[6] + ltv[7] * bp[7];
    float xnew = X[(size_t)row * 1024 + c] + s + bias[c];
    X[(size_t)row * 1024 + c] = xnew;
    v[i] = xnew;
  }
  // layernorm
  float sum = v[0] + v[1] + v[2] + v[3];
#pragma unroll
  for (int s = 32; s; s >>= 1) sum += __shfl_down(sum, s);
  if ((tid & 63) == 0) red[tid >> 6] = sum;
  __syncthreads();
  float mean = (red[0] + red[1] + red[2] + red[3]) * (1.f / 1024.f);
  __syncthreads();
  float sq = 0.f;
#pragma unroll
  for (int i = 0; i < 4; ++i) { float d = v[i] - mean; sq += d * d; }
#pragma unroll
  for (int s = 32; s; s >>= 1) sq += __shfl_down(sq, s);
  if ((tid & 63) == 0) red[tid >> 6] = sq;
  __syncthreads();
  float var = (red[0] + red[1] + red[2] + red[3]) * (1.f / 1024.f);
  float inv = rsqrtf(var + 1e-5f);
  float* orow = out + (size_t)row * 1024;
  float nv[4];
#pragma unroll
  for (int i = 0; i < 4; ++i) {
    const int c = tid + 256 * i;
    nv[i] = (v[i] - mean) * inv * g[c] + bt[c];
    orow[c] = nv[i];
  }
  __syncthreads();
  for (int z = 0; z < nz; ++z) {
    const float* Am = (z == 0) ? A0 : (z == 1) ? A1 : A2;
    float p[8];
#pragma unroll
    for (int r = 0; r < 8; ++r) {
      float s = 0.f;
#pragma unroll
      for (int i = 0; i < 4; ++i) s += nv[i] * Am[r * 1024 + tid + 256 * i];
      p[r] = s;
    }
#pragma unroll
    for (int sh = 1; sh < 64; sh <<= 1) {
#pragma unroll
      for (int r = 0; r < 8; ++r) p[r] += __shfl_xor(p[r], sh);
    }
    if (lane == 0) {
#pragma unroll
      for (int r = 0; r < 8; ++r) red2[wave][r] = p[r];
    }
    __syncthreads();
    if (tid < 8)
      lt[((size_t)z * NTOK + row) * 8 + tid] =
          red2[0][tid] + red2[1][tid] + red2[2][tid] + red2[3][tid];
    __syncthreads();
  }
}

// ============ small-M fp32 GEMM v2 (M=32) with K-split ==========================
__global__ __launch_bounds__(256) void gemm_sm2(const float* __restrict__ A, int lda,
                                                const float* __restrict__ W, int ldw,
                                                const float* __restrict__ bias,
                                                float* __restrict__ C, int ldc,
                                                float* __restrict__ part,
                                                int N, int K, int gelu_flag) {
  __shared__ float buf[8192];
  const int tid = threadIdx.x;
  const int col = tid >> 3, ksub = tid & 7;
  const int gcol = blockIdx.x * 32 + col;
  const int KS = gridDim.y, ky = blockIdx.y;
  const int kchunk = (((K + KS - 1) / KS) + 127) & ~127;
  const int kstart = ky * kchunk;
  const int kend = (kstart + kchunk < K) ? (kstart + kchunk) : K;
  const float* wp = W + (size_t)(gcol < N ? gcol : 0) * ldw;

  float acc[32];
#pragma unroll
  for (int m = 0; m < 32; ++m) acc[m] = 0.f;

  for (int kc = kstart; kc < kend; kc += 128) {
    __syncthreads();
#pragma unroll
    for (int q = 0; q < 4; ++q) {
      const int idx4 = q * 256 + tid;
      const int m = idx4 >> 5, j = (idx4 & 31) * 4;
      const int gk = kc + j;
      float4 v;
      if (gk + 3 < K) {
        v = *(const float4*)(A + (size_t)m * lda + gk);
      } else {
        v.x = (gk < K) ? A[(size_t)m * lda + gk] : 0.f;
        v.y = (gk + 1 < K) ? A[(size_t)m * lda + gk + 1] : 0.f;
        v.z = (gk + 2 < K) ? A[(size_t)m * lda + gk + 2] : 0.f;
        v.w = (gk + 3 < K) ? A[(size_t)m * lda + gk + 3] : 0.f;
      }
      *(float4*)&buf[m * 128 + j] = v;
    }
    __syncthreads();
#pragma unroll
    for (int kk = 0; kk < 4; ++kk) {
      const int j = kk * 32 + ksub * 4;
      const int gk = kc + j;
      float4 w4 = make_float4(0.f, 0.f, 0.f, 0.f);
      if (gcol < N && gk < K) {
        if (gk + 3 < K) {
          w4 = *(const float4*)(wp + gk);
        } else {
          w4.x = wp[gk];
          if (gk + 1 < K) w4.y = wp[gk + 1];
          if (gk + 2 < K) w4.z = wp[gk + 2];
        }
      }
#pragma unroll
      for (int m = 0; m < 32; ++m) {
        const float4 a4 = *(const float4*)&buf[m * 128 + j];
        acc[m] += a4.x * w4.x + a4.y * w4.y + a4.z * w4.z + a4.w * w4.w;
      }
    }
  }
  __syncthreads();
#pragma unroll
  for (int m = 0; m < 32; ++m) buf[m * 256 + ksub * 32 + col] = acc[m];
  __syncthreads();
#pragma unroll
  for (int g = 0; g < 4; ++g) {
    const int idx = g * 256 + tid;
    const int m = idx >> 5, c = idx & 31;
    float s = 0.f;
#pragma unroll
    for (int h = 0; h < 8; ++h) s += buf[m * 256 + h * 32 + c];
    const int gc = blockIdx.x * 32 + c;
    if (gc < N) {
      if (KS == 1) {
        float o = s + bias[gc];
        if (gelu_flag) o = gelu_f(o);
        C[(size_t)m * ldc + gc] = o;
      } else {
        part[((size_t)ky * 32 + m) * N + gc] = s;
      }
    }
  }
}

__global__ __launch_bounds__(256) void reduce_sm(const float* __restrict__ part,
                                                 const float* __restrict__ bias,
                                                 float* __restrict__ C, int ldc,
                                                 int N, int KS, int gelu_flag) {
  const int idx = blockIdx.x * 256 + threadIdx.x;
  if (idx >= 32 * N) return;
  const int m = idx / N, c = idx - m * N;
  float s = 0.f;
  for (int h = 0; h < KS; ++h) s += part[((size_t)h * 32 + m) * N + c];
  float o = s + bias[c];
  if (gelu_flag) o = gelu_f(o);
  C[(size_t)m * ldc + c] = o;
}

// ============ sims ==============================================================
__global__ __launch_bounds__(256) void sims_kernel(const float* __restrict__ cur,
                                                   const float* __restrict__ bank,
                                                   float* __restrict__ sims) {
  __shared__ float Bs[32][132];
  __shared__ float Cs[32][36];
  const int tid = threadIdx.x;
  const int tx = tid & 7;
  const int ty = tid >> 3;
  const int n0 = blockIdx.x * 128;
  const int srow = tid >> 1;
  const int spart = tid & 1;
  const int cb = tid >> 3;
  const int ck = (tid & 7) * 4;

  float acc[4][4] = {{0.f,0.f,0.f,0.f},{0.f,0.f,0.f,0.f},
                     {0.f,0.f,0.f,0.f},{0.f,0.f,0.f,0.f}};

  const bool rok = (n0 + srow) < NB;
  const float* bp = bank + (size_t)(n0 + srow) * 768 + spart * 16;
  const float* cp = cur + (size_t)cb * 768 + ck;

  for (int kc = 0; kc < 768; kc += 32) {
    __syncthreads();
#pragma unroll
    for (int jj = 0; jj < 4; ++jj) {
      float4 v = rok ? *(const float4*)(bp + kc + jj * 4)
                     : make_float4(0.f, 0.f, 0.f, 0.f);
      const int kk = spart * 16 + jj * 4;
      Bs[kk + 0][srow] = v.x; Bs[kk + 1][srow] = v.y;
      Bs[kk + 2][srow] = v.z; Bs[kk + 3][srow] = v.w;
    }
    {
      float4 v = *(const float4*)(cp + kc);
      Cs[ck + 0][cb] = v.x; Cs[ck + 1][cb] = v.y;
      Cs[ck + 2][cb] = v.z; Cs[ck + 3][cb] = v.w;
    }
    __syncthreads();
#pragma unroll
    for (int kk = 0; kk < 32; ++kk) {
      float4 av = *(const float4*)&Bs[kk][ty * 4];
      float4 bv = *(const float4*)&Cs[kk][tx * 4];
      float a4[4] = {av.x, av.y, av.z, av.w};
      float b4[4] = {bv.x, bv.y, bv.z, bv.w};
#pragma unroll
      for (int i = 0; i < 4; ++i)
#pragma unroll
        for (int j = 0; j < 4; ++j) acc[i][j] += a4[i] * b4[j];
    }
  }
  const int n = n0 + ty * 4;
#pragma unroll
  for (int j = 0; j < 4; ++j) {
    const int b = tx * 4 + j;
    float4 o = make_float4(acc[0][j], acc[1][j], acc[2][j], acc[3][j]);
    if (n + 3 < NB) {
      *(float4*)(sims + (size_t)b * NB + n) = o;
    } else {
      float oo[4] = {o.x, o.y, o.z, o.w};
      for (int i = 0; i < 4; ++i)
        if (n + i < NB) sims[(size_t)b * NB + n + i] = oo[i];
    }
  }
}

// ===================== top-K ====================================================
__global__ __launch_bounds__(256) void topk_stage1(const float* __restrict__ sims,
                                                   float* __restrict__ cv,
                                                   int* __restrict__ ci) {
  __shared__ float ss[4096];
  __shared__ int si[4096];
  __shared__ float wv[4];
  __shared__ int wi[4];
  const int chunk = blockIdx.x, b = blockIdx.y, tid = threadIdx.x;
  const int start = chunk * (NB / TKCH), end = start + (NB / TKCH);
  float ls[16]; int li[16];
#pragma unroll
  for (int i = 0; i < 16; ++i) { ls[i] = -FLT_MAX; li[i] = 0x7fffffff; }
  const float* row = sims + (size_t)b * NB;
  float lmin = -FLT_MAX;
  for (int n = start + tid; n < end; n += 256) {
    float v = row[n];
    if (v > lmin) {
      int p = 15;
      while (p > 0 && ls[p - 1] < v) { ls[p] = ls[p - 1]; li[p] = li[p - 1]; --p; }
      ls[p] = v; li[p] = n;
      lmin = ls[15];
    }
  }
#pragma unroll
  for (int i = 0; i < 16; ++i) { ss[i * 256 + tid] = ls[i]; si[i * 256 + tid] = li[i]; }
  __syncthreads();
  for (int round = 0; round < 16; ++round) {
    float bv = -FLT_MAX; int bi = 0x7fffffff;
#pragma unroll
    for (int i = 0; i < 16; ++i) {
      float v = ss[i * 256 + tid]; int ix = si[i * 256 + tid];
      if (v > bv || (v == bv && ix < bi)) { bv = v; bi = ix; }
    }
#pragma unroll
    for (int s = 32; s; s >>= 1) {
      float ov = __shfl_down(bv, s); int oi = __shfl_down(bi, s);
      if (ov > bv || (ov == bv && oi < bi)) { bv = ov; bi = oi; }
    }
    if ((tid & 63) == 0) { wv[tid >> 6] = bv; wi[tid >> 6] = bi; }
    __syncthreads();
    if (tid == 0) {
      bv = wv[0]; bi = wi[0];
      for (int w = 1; w < 4; ++w)
        if (wv[w] > bv || (wv[w] == bv && wi[w] < bi)) { bv = wv[w]; bi = wi[w]; }
      cv[(b * TKCH + chunk) * 16 + round] = bv;
      ci[(b * TKCH + chunk) * 16 + round] = bi;
      wi[0] = bi;
    }
    __syncthreads();
    bi = wi[0];
#pragma unroll
    for (int i = 0; i < 16; ++i)
      if (si[i * 256 + tid] == bi) ss[i * 256 + tid] = -FLT_MAX;
    __syncthreads();
  }
}

__global__ __launch_bounds__(256) void topk_stage2(const float* __restrict__ cv,
                                                   const int* __restrict__ ci,
                                                   float* __restrict__ tks,
                                                   int* __restrict__ tki) {
  __shared__ float wv[4];
  __shared__ int wi[4];
  __shared__ int bw;
  const int b = blockIdx.x, tid = threadIdx.x;
  float val = cv[b * 256 + tid];
  int idx = ci[b * 256 + tid];
  for (int round = 0; round < 16; ++round) {
    float bv = val; int bi = idx;
#pragma unroll
    for (int s = 1; s < 64; s <<= 1) {
      float ov = __shfl_xor(bv, s); int oi = __shfl_xor(bi, s);
      if (ov > bv || (ov == bv && oi < bi)) { bv = ov; bi = oi; }
    }
    if ((tid & 63) == 0) { wv[tid >> 6] = bv; wi[tid >> 6] = bi; }
    __syncthreads();
    if (tid == 0) {
      bv = wv[0]; bi = wi[0];
      for (int w = 1; w < 4; ++w)
        if (wv[w] > bv || (wv[w] == bv && wi[w] < bi)) { bv = wv[w]; bi = wi[w]; }
      tks[b * 16 + round] = bv; tki[b * 16 + round] = bi;
      bw = bi;
    }
    __syncthreads();
    if (idx == bw) val = -FLT_MAX;
  }
}

// ===================== small copy/assembly kernels ==============================
// writes directly into img_in rows 96..607 (dst = AOb + 96*768)
__global__ void sem_kernel(const float* __restrict__ bank, const float* __restrict__ tks,
                           const int* __restrict__ tki, float* __restrict__ sem) {
  int slot = blockIdx.x;
  float s = tks[slot]; int idx = tki[slot];
  for (int i = threadIdx.x; i < 768; i += 256)
    sem[(size_t)slot * 768 + i] = bank[(size_t)idx * 768 + i] * s;
}

// HIN stride 832, zero-padded k>=777
__global__ void build_hist_in(const float* __restrict__ img, const float* __restrict__ pr,
                              float* __restrict__ out) {
  int r = blockIdx.x;
  for (int i = threadIdx.x; i < 832; i += 256)
    out[(size_t)r * 832 + i] = (i < 768) ? img[(size_t)r * 768 + i]
                             : (i < 777) ? pr[r * 9 + (i - 768)] : 0.f;
}

// only goal/sub/bea (96 rows); sem rows written directly by sem_kernel
__global__ void build_img_in(const float* __restrict__ goal, const float* __restrict__ sub,
                             const float* __restrict__ bea, float* __restrict__ out) {
  int r = blockIdx.x;  // 0..95
  const float* src = (r < 32) ? goal + (size_t)r * 768
                   : (r < 64) ? sub + (size_t)(r - 32) * 768
                              : bea + (size_t)(r - 64) * 768;
  for (int i = threadIdx.x; i < 768; i += 256) out[(size_t)r * 768 + i] = src[i];
}

__global__ void assemble_x(const float* __restrict__ th, const float* __restrict__ ti,
                           const float* __restrict__ tp, const float* __restrict__ plan,
                           float* __restrict__ x) {
  int r = blockIdx.x;
  int b = r / SEQ, tok = r - b * SEQ;
  const float* src;
  if (tok == 0) src = plan;
  else if (tok <= 16) src = th + (size_t)(b * 16 + tok - 1) * 1024;
  else if (tok <= 19) src = ti + (size_t)((tok - 17) * 32 + b) * 1024;
  else if (tok <= 35) src = ti + (size_t)(96 + b * 16 + (tok - 20)) * 1024;
  else src = tp + (size_t)b * 1024;
  for (int i = threadIdx.x; i < 1024; i += 256) x[(size_t)r * 1024 + i] = src[i];
}

__global__ void build_ref(const float* __restrict__ ps, const float* __restrict__ anc,
                          float* __restrict__ ref) {
  int b = blockIdx.x;
  for (int i = threadIdx.x; i < 1027; i += 256)
    ref[(size_t)b * 1027 + i] = (i < 1024) ? ps[(size_t)b * 1024 + i] : anc[b * 3 + (i - 1024)];
}

// ===================== layernorm (+fused LoRA-down, nz matrices) ===============
__device__ __forceinline__ float block_sum256(float v, float* red) {
#pragma unroll
  for (int s = 32; s; s >>= 1) v += __shfl_down(v, s);
  if ((threadIdx.x & 63) == 0) red[threadIdx.x >> 6] = v;
  __syncthreads();
  float tot = red[0] + red[1] + red[2] + red[3];
  __syncthreads();
  return tot;
}

__global__ __launch_bounds__(256) void ln_kernel(const float* __restrict__ in, int in_stride,
                                                 float* __restrict__ out,
                                                 const float* __restrict__ g,
                                                 const float* __restrict__ bt,
                                                 const float* __restrict__ A0,
                                                 const float* __restrict__ A1,
                                                 const float* __restrict__ A2,
                                                 int nz, float* __restrict__ lt) {
  __shared__ float red[4];
  __shared__ float red2[4][8];
  const float* xr = in + (size_t)blockIdx.x * in_stride;
  const int tid = threadIdx.x;
  const int wave = tid >> 6, lane = tid & 63;
  float v[4];
#pragma unroll
  for (int i = 0; i < 4; ++i) v[i] = xr[tid + 256 * i];
  float mean = block_sum256(v[0] + v[1] + v[2] + v[3], red) * (1.f / 1024.f);
  float sq = 0.f;
#pragma unroll
  for (int i = 0; i < 4; ++i) { float d = v[i] - mean; sq += d * d; }
  float var = block_sum256(sq, red) * (1.f / 1024.f);
  float inv = rsqrtf(var + 1e-5f);
  float* orow = out + (size_t)blockIdx.x * 1024;
  float nv[4];
#pragma unroll
  for (int i = 0; i < 4; ++i) {
    int c = tid + 256 * i;
    nv[i] = (v[i] - mean) * inv * g[c] + bt[c];
    orow[c] = nv[i];
  }
  for (int z = 0; z < nz; ++z) {
    const float* Am = (z == 0) ? A0 : (z == 1) ? A1 : A2;
    float p[8];
#pragma unroll
    for (int r = 0; r < 8; ++r) {
      float s = 0.f;
#pragma unroll
      for (int i = 0; i < 4; ++i) s += nv[i] * Am[r * 1024 + tid + 256 * i];
      p[r] = s;
    }
#pragma unroll
    for (int sh = 1; sh < 64; sh <<= 1) {
#pragma unroll
      for (int r = 0; r < 8; ++r) p[r] += __shfl_xor(p[r], sh);
    }
    if (lane == 0) {
#pragma unroll
      for (int r = 0; r < 8; ++r) red2[wave][r] = p[r];
    }
    __syncthreads();
    if (tid < 8)
      lt[((size_t)z * NTOK + blockIdx.x) * 8 + tid] =
          red2[0][tid] + red2[1][tid] + red2[2][tid] + red2[3][tid];
    __syncthreads();
  }
}

// ===================== LoRA down (standalone, for o/f2 inputs) ==================
__global__ __launch_bounds__(256) void lora_down(const float* __restrict__ h,
                                                 const float* __restrict__ A0,
                                                 const float* __restrict__ A1,
                                                 const float* __restrict__ A2,
                                                 float* __restrict__ lt, int K) {
  __shared__ float red[4][8];
  const int m = blockIdx.x, z = blockIdx.y;
  const int tid = threadIdx.x, wave = tid >> 6, lane = tid & 63;
  const float* A = (z == 0) ? A0 : (z == 1) ? A1 : A2;
  float p[8] = {0.f, 0.f, 0.f, 0.f, 0.f, 0.f, 0.f, 0.f};
  for (int kk = tid; kk < K; kk += 256) {
    float hv = h[(size_t)m * K + kk];
#pragma unroll
    for (int r = 0; r < 8; ++r) p[r] += hv * A[r * K + kk];
  }
#pragma unroll
  for (int s = 1; s < 64; s <<= 1) {
#pragma unroll
    for (int r = 0; r < 8; ++r) p[r] += __shfl_xor(p[r], s);
  }
  if (lane == 0) {
#pragma unroll
    for (int r = 0; r < 8; ++r) red[wave][r] = p[r];
  }
  __syncthreads();
  if (tid < 8)
    lt[((size_t)z * NTOK + m) * 8 + tid] =
        red[0][tid] + red[1][tid] + red[2][tid] + red[3][tid];
}

// ===================== attention ================================================
__global__ __launch_bounds__(256) void attn_kernel(const float* __restrict__ q,
                                                   const float* __restrict__ k,
                                                   const float* __restrict__ v,
                                                   float* __restrict__ ao) {
  __shared__ float qs[SEQ * 64], ks[SEQ * 64], vs[SEQ * 64], sc[SEQ * 40];
  const int head = blockIdx.x, b = blockIdx.y, tid = threadIdx.x;
  const size_t base = ((size_t)b * SEQ) * 1024 + head * 64;
  for (int i = tid; i < SEQ * 64; i += 256) {
    int s = i >> 6, d = i & 63;
    size_t off = base + (size_t)s * 1024 + d;
    qs[i] = q[off]; ks[i] = k[off]; vs[i] = v[off];
  }
  __syncthreads();
  for (int p = tid; p < SEQ * SEQ; p += 256) {
    int s = p / SEQ, t = p - s * SEQ;
    float acc = 0.f;
#pragma unroll 16
    for (int d = 0; d < 64; ++d) acc += qs[s * 64 + d] * ks[t * 64 + d];
    sc[s * 40 + t] = acc * 0.125f;
  }
  __syncthreads();
  if (tid < SEQ) {
    float m = -FLT_MAX;
    for (int t = 0; t < SEQ; ++t) m = fmaxf(m, sc[tid * 40 + t]);
    float sum = 0.f;
    for (int t = 0; t < SEQ; ++t) { float e = expf(sc[tid * 40 + t] - m); sc[tid * 40 + t] = e; sum += e; }
    float inv = 1.f / sum;
    for (int t = 0; t < SEQ; ++t) sc[tid * 40 + t] *= inv;
  }
  __syncthreads();
  for (int i = tid; i < SEQ * 64; i += 256) {
    int s = i >> 6, d = i & 63;
    float acc = 0.f;
    for (int t = 0; t < SEQ; ++t) acc += sc[s * 40 + t] * vs[t * 64 + d];
    ao[base + (size_t)s * 1024 + d] = acc;
  }
}

// ===================== host =====================================================
extern "C" void kernel_launch(void* const* d_in, const int* in_sizes, int n_in,
                              void* d_out, int out_size, void* d_ws, size_t ws_size,
                              hipStream_t stream) {
  const float* hist_img = (const float*)d_in[0];
  const float* cur      = (const float*)d_in[1];
  const float* goal     = (const float*)d_in[2];
  const float* sub      = (const float*)d_in[3];
  const float* bea      = (const float*)d_in[4];
  const float* hist_pr  = (const float*)d_in[5];
  const float* prop     = (const float*)d_in[6];
  const float* bank     = (const float*)d_in[7];
  const float* hpW = (const float*)d_in[8];  const float* hpb = (const float*)d_in[9];
  const float* ipW = (const float*)d_in[10]; const float* ipb = (const float*)d_in[11];
  const float* ppW = (const float*)d_in[12]; const float* ppb = (const float*)d_in[13];
  const float* plan = (const float*)d_in[14];
  const float* ln1g = (const float*)d_in[15]; const float* ln1b = (const float*)d_in[16];
  const float* ln2g = (const float*)d_in[17]; const float* ln2b = (const float*)d_in[18];
  const float* qW = (const float*)d_in[19]; const float* qA = (const float*)d_in[20];
  const float* qB = (const float*)d_in[21]; const float* qb = (const float*)d_in[22];
  const float* kW = (const float*)d_in[23]; const float* kA = (const float*)d_in[24];
  const float* kB = (const float*)d_in[25]; const float* kb = (const float*)d_in[26];
  const float* vW = (const float*)d_in[27]; const float* vA = (const float*)d_in[28];
  const float* vB = (const float*)d_in[29]; const float* vb = (const float*)d_in[30];
  const float* oW = (const float*)d_in[31]; const float* oA = (const float*)d_in[32];
  const float* oB = (const float*)d_in[33]; const float* ob = (const float*)d_in[34];
  const float* f1W = (const float*)d_in[35]; const float* f1A = (const float*)d_in[36];
  const float* f1B = (const float*)d_in[37]; const float* f1b = (const float*)d_in[38];
  const float* f2W = (const float*)d_in[39]; const float* f2A = (const float*)d_in[40];
  const float* f2B = (const float*)d_in[41]; const float* f2b = (const float*)d_in[42];
  const float* flng = (const float*)d_in[43]; const float* flnb = (const float*)d_in[44];
  const float* ahW1 = (const float*)d_in[45]; const float* ahb1 = (const float*)d_in[46];
  const float* ahW2 = (const float*)d_in[47]; const float* ahb2 = (const float*)d_in[48];
  const float* rhW1 = (const float*)d_in[49]; const float* rhb1 = (const float*)d_in[50];
  const float* rhW2 = (const float*)d_in[51]; const float* rhb2 = (const float*)d_in[52];
  const float* shW = (const float*)d_in[53]; const float* shb = (const float*)d_in[54];
  float* out = (float*)d_out;

  float* ws  = (float*)d_ws;
  float* F1O = ws;
  float* SIMS = ws;
  float* X   = F1O + (size_t)NTOK * 4096;
  float* Hb  = X  + (size_t)NTOK * 1024;
  float* Qb  = Hb + (size_t)NTOK * 1024;
  float* Kb  = Qb + (size_t)NTOK * 1024;
  float* Vb  = Kb + (size_t)NTOK * 1024;
  float* AOb = Vb + (size_t)NTOK * 1024;
  float* LT  = AOb + (size_t)NTOK * 1024;      // 3*NTOK*8
  float* SEM = LT + (size_t)3 * NTOK * 8;      // (unused, layout kept)
  float* HIN = SEM + (size_t)512 * 768;        // 512*832 (padded)
  float* TKS = HIN + (size_t)512 * 832;
  int*   TKI = (int*)(TKS + 512);
  float* PS  = TKS + 1024;
  float* HH  = PS + 32 * 1024;
  float* REF = HH + 32 * 1024;
  float* CV  = REF + 32 * 1027;
  int*   CI  = (int*)(CV + 32 * 256);
  float* PART = (float*)(CI + 32 * 256);       // heads: 8*32*1024
  float* PF2 = PART + 8 * 32 * 1024;           // K-split partials: 4*NTOK*1024
  short* WB  = (short*)(PF2 + (size_t)4 * NTOK * 1024);  // 6*12M shorts
  short* WBE = WB + (size_t)6 * 12 * 1048576;  // embed: 200*8192 shorts

  const size_t czs = (size_t)NTOK * 1024;
  const size_t WM = 1048576;
  const size_t WL = 12 * WM;

  auto gemms = [&](const float* A, int lda, const float* W, int ldw, const float* bias,
                   float* C, int ldc, int N, int K, int geluf, int KS) {
    gemm_sm2<<<dim3((N + 31) / 32, KS), 256, 0, stream>>>(A, lda, W, ldw, bias,
                                                          C, ldc, PART, N, K, geluf);
    if (KS > 1)
      reduce_sm<<<(32 * N + 255) / 256, 256, 0, stream>>>(PART, bias, C, ldc, N, KS, geluf);
  };

  // ---- weight conversions ----
  wconv_all<<<6 * 1536, 256, 0, stream>>>(qW, kW, vW, oW, f1W, f2W, WB);
  wconv_embed<<<200, 256, 0, stream>>>(hpW, ipW, WBE);

  // ---- retrieval ----
  sims_kernel<<<(NB + 127) / 128, 256, 0, stream>>>(cur, bank, SIMS);
  topk_stage1<<<dim3(TKCH, 32), 256, 0, stream>>>(SIMS, CV, CI);
  topk_stage2<<<32, 256, 0, stream>>>(CV, CI, TKS, TKI);
  sem_kernel<<<512, 256, 0, stream>>>(bank, TKS, TKI, AOb + (size_t)96 * 768);

  // ---- token embedding (tiled bf16 GEMMs) ----
  build_hist_in<<<512, 256, 0, stream>>>(hist_img, hist_pr, HIN);
  build_img_in<<<96, 256, 0, stream>>>(goal, sub, bea, AOb);
  gemm_bt<<<dim3(8, 8, 1), 256, 0, stream>>>(
      HIN, 832, WBE, 0, hpb, hpb, hpb,
      nullptr, nullptr, nullptr, nullptr, Qb, 0, 1024, 512, 832, 0, 0, 1, nullptr);
  gemm_bt<<<dim3(10, 8, 1), 256, 0, stream>>>(
      AOb, 768, WBE + (size_t)104 * 8192, 0, ipb, ipb, ipb,
      nullptr, nullptr, nullptr, nullptr, Kb, 0, 1024, 608, 768, 0, 0, 1, nullptr);
  gemms(prop, 9, ppW, 9, ppb, Vb, 1024, 1024, 9, 0, 1);
  assemble_x<<<NTOK, 256, 0, stream>>>(Qb, Kb, Vb, plan, X);

  // ---- transformer layers ----
  const int mblk = (NTOK + 63) / 64;  // 19
  // ln1 of layer 0 (+qkv lora-down)
  ln_kernel<<<NTOK, 256, 0, stream>>>(X, 1024, Hb, ln1g, ln1b, qA, kA, vA, 3, LT);
  for (int l = 0; l < 6; ++l) {
    const size_t aO = (size_t)l * 8 * 1024, bO = (size_t)l * 1024 * 8,
                 biO = (size_t)l * 1024;
    const size_t a4O = (size_t)l * 8 * 4096, b4O = (size_t)l * 4096 * 8,
                 bi4O = (size_t)l * 4096;
    const short* WBl = WB + (size_t)l * WL;
    gemm_bt<<<dim3(mblk, 8, 3), 256, 0, stream>>>(
        Hb, 1024, WBl, WM, qb + biO, kb + biO, vb + biO,
        LT, qB + bO, kB + bO, vB + bO, Qb, czs, 1024, NTOK, 1024, 0, 0, 1, nullptr);
    attn_kernel<<<dim3(16, 32), 256, 0, stream>>>(Qb, Kb, Vb, AOb);
    lora_down<<<dim3(NTOK, 1), 256, 0, stream>>>(AOb, oA + aO, oA + aO, oA + aO, LT, 1024);
    gemm_bt<<<dim3(mblk, 8, 2), 256, 0, stream>>>(        // o: K-split x2
        AOb, 1024, WBl + 3 * WM, 0, ob + biO, ob + biO, ob + biO,
        nullptr, nullptr, nullptr, nullptr, nullptr, 0, 1024, NTOK, 1024, 0, 0, 2, PF2);
    // fused: o-reduce + residual + ln2 + f1 lora-down
    redln<<<NTOK, 256, 0, stream>>>(PF2, 2, ob + biO, oB + bO, X, Hb,
                                    ln2g + biO, ln2b + biO,
                                    f1A + aO, f1A + aO, f1A + aO, 1, LT);
    gemm_bt<<<dim3(mblk, 32, 1), 256, 0, stream>>>(
        Hb, 1024, WBl + 4 * WM, 0, f1b + bi4O, f1b + bi4O, f1b + bi4O,
        LT, f1B + b4O, f1B + b4O, f1B + b4O, F1O, 0, 4096, NTOK, 1024, 0, 1, 1, nullptr);
    lora_down<<<dim3(NTOK, 1), 256, 0, stream>>>(F1O, f2A + a4O, f2A + a4O, f2A + a4O, LT, 4096);
    gemm_bt<<<dim3(mblk, 8, 4), 256, 0, stream>>>(        // f2: K-split x4
        F1O, 4096, WBl + 8 * WM, 0, f2b + biO, f2b + biO, f2b + biO,
        nullptr, nullptr, nullptr, nullptr, nullptr, 0, 1024, NTOK, 4096, 0, 0, 4, PF2);
    if (l < 5) {
      // fused: f2-reduce + residual + next-layer ln1 + qkv lora-down
      redln<<<NTOK, 256, 0, stream>>>(PF2, 4, f2b + biO, f2B + bO, X, Hb,
                                      ln1g + biO + 1024, ln1b + biO + 1024,
                                      qA + aO + 8192, kA + aO + 8192, vA + aO + 8192,
                                      3, LT);
    } else {
      reduce_ks<<<(NTOK * 1024 + 255) / 256, 256, 0, stream>>>(PF2, f2b + biO, LT,
                                                               f2B + bO, X, 4);
    }
  }

  // ---- heads ----
  ln_kernel<<<32, 256, 0, stream>>>(X, SEQ * 1024, PS, flng, flnb,
                                    nullptr, nullptr, nullptr, 0, nullptr);
  gemms(PS, 1024, ahW1, 1024, ahb1, HH, 1024, 1024, 1024, 1, 8);
  gemms(HH, 1024, ahW2, 1024, ahb2, out, 3, 3, 1024, 0, 8);
  build_ref<<<32, 256, 0, stream>>>(PS, out, REF);
  gemms(REF, 1027, rhW1, 1027, rhb1, HH, 1024, 1024, 1027, 1, 8);
  gemms(HH, 1024, rhW2, 1024, rhb2, out + 96, 24, 24, 1024, 0, 8);
  gemms(PS, 1024, shW, 1024, shb, out + 864, 1, 1, 1024, 0, 8);
}